// Round 4
// baseline (3285.926 us; speedup 1.0000x reference)
//
#include <hip/hip_runtime.h>
#include <cmath>

// One workgroup (512 threads) per sample.
// VERBATIM the R3 passing kernel (absmax 4096) with ONE change:
//   __launch_bounds__(512, 8): force VGPR <= 64 so 4 blocks (32 waves) fit
//   per CU (was 84 VGPR -> 4 waves/SIMD -> 2 blocks/CU). No arithmetic change.
__global__ __launch_bounds__(512, 8)
void leql_f32_kernel(const float* __restrict__ x,
                     const float* __restrict__ W0g, const float* __restrict__ b0g,
                     const float* __restrict__ W1g, const float* __restrict__ b1g,
                     const float* __restrict__ Wog, const float* __restrict__ bog,
                     float* __restrict__ out, int B)
{
    __shared__ float uf[32];
    __shared__ float WoS[1024];
    __shared__ float z0f[512], z1f[512];
    __shared__ float s0f[256], c0f[256], s1f[256], c1f[256];
    __shared__ float h1df[512];
    __shared__ float whatf[384];
    __shared__ float v0f[384];
    __shared__ float tmpf[512];          // also holds h0, then h1 (aliased)
    __shared__ float hd0f[384];
    __shared__ float zd1f[512];
    __shared__ float vd0f[384];
    __shared__ float Hf[32][17];
    __shared__ float yvf[2], ydf[2];
    __shared__ float Af[16][33], rf[16], qdo[16];
    __shared__ float wkc[16];
    __shared__ int ipiv[16];
    __shared__ int pivS;

    const int t = threadIdx.x;
    const int s = blockIdx.x;

    if (t < 32) uf[t] = x[s*32 + t];
    WoS[t] = Wog[t]; WoS[512+t] = Wog[512+t];
    __syncthreads();

    // ---- forward ----
    {
        const float* wr = &W0g[(128+t)*32];
        float acc = 0.0f;
        for (int c = 0; c < 32; ++c) acc = fmaf(wr[c], uf[c], acc);
        z0f[t] = __fadd_rn(acc, b0g[128+t]);
    }
    __syncthreads();
    if (t < 256) { s0f[t] = sinf(z0f[t]); c0f[t] = cosf(z0f[t]); }
    __syncthreads();
    if (t < 128)      tmpf[t] = 1.0f;                          // h0
    else if (t < 256) tmpf[t] = s0f[t-128];
    else if (t < 384) tmpf[t] = c0f[t-128];
    else              tmpf[t] = __fmul_rn(z0f[t-128], z0f[t]);
    __syncthreads();
    {
        const float* wr = &W1g[(size_t)(128+t)*512];
        float acc = 0.0f;
        for (int m = 0; m < 512; ++m) acc = fmaf(wr[m], tmpf[m], acc);
        z1f[t] = __fadd_rn(acc, b1g[128+t]);
    }
    __syncthreads();
    if (t < 256) { s1f[t] = sinf(z1f[t]); c1f[t] = cosf(z1f[t]); }
    __syncthreads();
    if (t < 128)      tmpf[t] = 1.0f;                          // h1
    else if (t < 256) tmpf[t] = s1f[t-128];
    else if (t < 384) tmpf[t] = c1f[t-128];
    else              tmpf[t] = __fmul_rn(z1f[t-128], z1f[t]);
    __syncthreads();
    if (t < 2) {
        float acc = 0.0f;
        for (int n = 0; n < 512; ++n) acc = fmaf(WoS[t*512 + n], tmpf[n], acc);
        yvf[t] = __fadd_rn(acc, bog[t]);
    }
    __syncthreads();

    // ---- quotient-rule seeds, jax-lax form ----
    const float y1 = yvf[0], y2 = yvf[1];

    // theta-gate early exit: for y2 <= 0.5 the reference where() zeroes the
    // cotangent exactly (jcob = h1 = h2 = 0), so qdd = inv(eps I) @ 0 = 0 and
    // lg = 0 -- identical to what the original kernel wrote for these samples.
    if (!(y2 > 0.5f)) {
        if (t < 16)  out[s*16 + t] = 0.0f;
        if (t == 16) out[(size_t)B*16 + s] = 0.0f;
        if (t == 17) out[(size_t)B*17 + s] = y2;
        return;
    }

    const float y2sq = __fmul_rn(y2, y2);
    const float r2 = 1.0f / y2sq;                       // integer_pow(y2,-2)
    const float r3 = 1.0f / __fmul_rn(y2sq, y2);        // integer_pow(y2,-3)
    const float sd1f = 1.0f / y2;                       // div VJP wrt numerator
    const float sd2f = __fmul_rn(-y1, r2);              // mul(mul(neg(ct),y1),y2^-2)

    // ---- base reverse pass ----
    if (t < 384) {                                       // Wo^T @ seed: fmaf k-chain
        float acc = fmaf(WoS[128+t], sd1f, 0.0f);
        whatf[t] = fmaf(WoS[512+128+t], sd2f, acc);
    }
    __syncthreads();
    {
        float v;
        if (t < 128)      v =  __fmul_rn(whatf[t],     c1f[t]);
        else if (t < 256) v = -__fmul_rn(whatf[t],     s1f[t]);
        else if (t < 384) v =  __fmul_rn(whatf[t],     z1f[t+128]);
        else              v =  __fmul_rn(whatf[t-128], z1f[t-128]);
        tmpf[t] = v;
    }
    __syncthreads();
    if (t < 384) {
        const float* wc = &W1g[(size_t)128*512 + 128 + t];
        float acc = 0.0f;
        for (int p = 0; p < 512; ++p) acc = fmaf(tmpf[p], wc[(size_t)p*512], acc);
        v0f[t] = acc;
    }
    __syncthreads();
    {
        float v;
        if (t < 128)      v =  __fmul_rn(v0f[t],     c0f[t]);
        else if (t < 256) v = -__fmul_rn(v0f[t],     s0f[t]);
        else if (t < 384) v =  __fmul_rn(v0f[t],     z0f[t+128]);
        else              v =  __fmul_rn(v0f[t-128], z0f[t-128]);
        tmpf[t] = v;
    }
    __syncthreads();
    if (t < 32) {
        float acc = 0.0f;
        for (int p = 0; p < 512; ++p) acc = fmaf(tmpf[p], W0g[(128+p)*32 + t], acc);
        Hf[t][16] = acc;
    }
    __syncthreads();

    // ---- 16 tangent passes ----
    for (int j = 0; j < 16; ++j) {
        const int cj = 16 + j;
        if (t < 384) {
            float v;
            if (t < 128)      v =  __fmul_rn(c0f[t], W0g[(128+t)*32 + cj]);
            else if (t < 256) v = -__fmul_rn(s0f[t], W0g[(128+t)*32 + cj]);
            else {
                int i = t - 256;
                v = __fadd_rn(__fmul_rn(W0g[(384+i)*32 + cj], z0f[384+i]),
                              __fmul_rn(z0f[256+i], W0g[(512+i)*32 + cj]));
            }
            hd0f[t] = v;
        }
        __syncthreads();
        {
            const float* wr = &W1g[(size_t)(128+t)*512 + 128];
            float acc = 0.0f;
            for (int m = 0; m < 384; ++m) acc = fmaf(wr[m], hd0f[m], acc);
            zd1f[t] = acc;
        }
        __syncthreads();
        {
            float v;
            if (t < 128)      v = 0.0f;
            else if (t < 256) v =  __fmul_rn(c1f[t-128], zd1f[t-128]);
            else if (t < 384) v = -__fmul_rn(s1f[t-128], zd1f[t-128]);
            else              v = __fadd_rn(__fmul_rn(zd1f[t-128], z1f[t]),
                                            __fmul_rn(z1f[t-128], zd1f[t]));
            h1df[t] = v;
        }
        __syncthreads();
        if (t < 2) {
            float acc = 0.0f;
            for (int n = 0; n < 512; ++n) acc = fmaf(WoS[t*512 + n], h1df[n], acc);
            ydf[t] = acc;
        }
        __syncthreads();
        {   // vdot1, jax-JVP associations
            float yd1 = ydf[0], yd2 = ydf[1];
            float sdot1 = __fmul_rn(-yd2, r2);
            float dr2 = __fmul_rn(__fmul_rn(yd2, -2.0f), r3);
            float sdot2 = __fadd_rn(__fmul_rn(-yd1, r2), __fmul_rn(-y1, dr2));
            int n = (t < 384) ? (128 + t) : t;
            float wd = fmaf(WoS[512+n], sdot2, fmaf(WoS[n], sdot1, 0.0f));
            float v;
            if (t < 128) {                       // sin node: what*cos(z1)
                float dcs = __fmul_rn(zd1f[t], -s1f[t]);      // d(cos) = zd*(-sin)
                v = __fadd_rn(__fmul_rn(wd, c1f[t]), __fmul_rn(whatf[t], dcs));
            } else if (t < 256) {                // cos node: what*(-sin(z1))
                float dsn = __fmul_rn(zd1f[t], c1f[t]);       // d(sin) = zd*cos
                v = __fadd_rn(__fmul_rn(wd, -s1f[t]), __fmul_rn(whatf[t], -dsn));
            } else if (t < 384) {
                v = __fadd_rn(__fmul_rn(wd, z1f[t+128]),
                              __fmul_rn(whatf[t], zd1f[t+128]));
            } else {
                v = __fadd_rn(__fmul_rn(wd, z1f[t-128]),
                              __fmul_rn(whatf[t-128], zd1f[t-128]));
            }
            tmpf[t] = v;
        }
        __syncthreads();
        if (t < 384) {
            const float* wc = &W1g[(size_t)128*512 + 128 + t];
            float acc = 0.0f;
            for (int p = 0; p < 512; ++p) acc = fmaf(tmpf[p], wc[(size_t)p*512], acc);
            vd0f[t] = acc;
        }
        __syncthreads();
        {   // dzdot0, jax-JVP associations
            float v;
            if (t < 128) {                       // sin z0 node: v0*cos(z0)
                float e = W0g[(128+t)*32 + cj];
                float dcs = __fmul_rn(e, -s0f[t]);
                v = __fadd_rn(__fmul_rn(vd0f[t], c0f[t]), __fmul_rn(v0f[t], dcs));
            } else if (t < 256) {                // cos z0 node: v0*(-sin(z0))
                float e = W0g[(128+t)*32 + cj];
                float dsn = __fmul_rn(e, c0f[t]);
                v = __fadd_rn(__fmul_rn(vd0f[t], -s0f[t]), __fmul_rn(v0f[t], -dsn));
            } else if (t < 384) {
                float eb = W0g[(256+t)*32 + cj];
                v = __fadd_rn(__fmul_rn(vd0f[t], z0f[t+128]), __fmul_rn(v0f[t], eb));
            } else {
                float ea = W0g[t*32 + cj];
                v = __fadd_rn(__fmul_rn(vd0f[t-128], z0f[t-128]), __fmul_rn(v0f[t-128], ea));
            }
            tmpf[t] = v;
        }
        __syncthreads();
        if (t < 32) {
            float acc = 0.0f;
            for (int p = 0; p < 512; ++p) acc = fmaf(tmpf[p], W0g[(128+p)*32 + t], acc);
            Hf[t][j] = acc;
        }
        __syncthreads();
    }

    // ---- A = h1 + eps I; rhs = jcob - h2@q ----
    if (t < 256) {
        int i = t >> 4, jj = t & 15;
        Af[i][jj] = (i == jj) ? __fadd_rn(Hf[16+i][jj], 1.0e-3f) : Hf[16+i][jj];
    }
    if (t >= 256 && t < 272) {
        int i = t - 256;
        float dd = 0.0f;
        for (int jj = 0; jj < 16; ++jj) dd = fmaf(Hf[i][jj], uf[jj], dd);
        rf[i] = __fsub_rn(Hf[i][16], dd);
    }
    __syncthreads();

    // sgetf2
    for (int j = 0; j < 16; ++j) {
        if (t == 0) {
            int p = j; float best = fabsf(Af[j][j]);
            for (int r = j+1; r < 16; ++r) {
                float v = fabsf(Af[r][j]);
                if (v > best) { best = v; p = r; }
            }
            ipiv[j] = p; pivS = p;
        }
        __syncthreads();
        int piv = pivS;
        if (piv != j && t < 16) {
            float tv = Af[j][t]; Af[j][t] = Af[piv][t]; Af[piv][t] = tv;
        }
        __syncthreads();
        float recip = 1.0f / Af[j][j];
        if (t > j && t < 16) Af[t][j] = __fmul_rn(Af[t][j], recip);
        __syncthreads();
        if (t < 256) {
            int i = t >> 4, k = t & 15;
            if (i > j && k > j) Af[i][k] = fmaf(-Af[i][j], Af[j][k], Af[i][k]);
        }
        __syncthreads();
    }

    // sgetri: strti2 + descending-j sweep + reverse column pivots
    if (t == 0) {
        for (int j = 0; j < 16; ++j) {
            float ajj_inv = 1.0f / Af[j][j];
            Af[j][j] = ajj_inv;
            float ajj = -ajj_inv;
            for (int j2 = 0; j2 < j; ++j2) {
                float temp = Af[j2][j];
                if (temp != 0.0f)
                    for (int i = 0; i < j2; ++i)
                        Af[i][j] = fmaf(temp, Af[i][j2], Af[i][j]);
                Af[j2][j] = __fmul_rn(Af[j2][j], Af[j2][j2]);
            }
            for (int i = 0; i < j; ++i) Af[i][j] = __fmul_rn(Af[i][j], ajj);
        }
    }
    __syncthreads();
    for (int j = 15; j >= 0; --j) {
        if (t > j && t < 16) { wkc[t] = Af[t][j]; Af[t][j] = 0.0f; }
        __syncthreads();
        if (t < 16) {
            float acc = Af[t][j];
            for (int k = j+1; k < 16; ++k) acc = fmaf(-wkc[k], Af[t][k], acc);
            Af[t][j] = acc;
        }
        __syncthreads();
    }
    if (t < 16) {
        for (int j = 15; j >= 0; --j) {
            int jp = ipiv[j];
            if (jp != j) { float tv = Af[t][j]; Af[t][j] = Af[t][jp]; Af[t][jp] = tv; }
        }
    }
    __syncthreads();

    // qdd = inv @ rhs
    if (t < 16) {
        float acc = 0.0f;
        for (int jj = 0; jj < 16; ++jj) acc = fmaf(Af[t][jj], rf[jj], acc);
        qdo[t] = acc;
    }
    __syncthreads();

    // ---- outputs (gate is true on this path) ----
    if (t < 16)  out[s*16 + t] = qdo[t];
    if (t == 16) out[(size_t)B*16 + s] = y1 / y2;
    if (t == 17) out[(size_t)B*17 + s] = y2;
}

extern "C" void kernel_launch(void* const* d_in, const int* in_sizes, int n_in,
                              void* d_out, int out_size, void* d_ws, size_t ws_size,
                              hipStream_t stream) {
    (void)n_in; (void)out_size; (void)d_ws; (void)ws_size;
    const float* x  = (const float*)d_in[0];
    const float* W0 = (const float*)d_in[1];
    const float* b0 = (const float*)d_in[2];
    const float* W1 = (const float*)d_in[3];
    const float* b1 = (const float*)d_in[4];
    const float* Wo = (const float*)d_in[5];
    const float* bo = (const float*)d_in[6];
    const int B = in_sizes[0] / 32;
    hipLaunchKernelGGL(leql_f32_kernel, dim3(B), dim3(512), 0, stream,
                       x, W0, b0, W1, b1, Wo, bo, (float*)d_out, B);
}

// Round 5
// 1971.698 us; speedup vs baseline: 1.6665x; 1.6665x over previous
//
#include <hip/hip_runtime.h>
#include <cmath>

// One workgroup (512 threads) per sample.
// VERBATIM the R3 passing kernel (absmax 4096) with ONE change:
//   __launch_bounds__(512, 6): 6 waves/EU -> 3 blocks/CU, VGPR cap ~85 so the
//   natural 84-VGPR allocation still fits WITHOUT spilling (R4's (512,8) forced
//   VGPR=32 and spilled: WRITE_SIZE 256KB -> 20MB, perf regressed).
__global__ __launch_bounds__(512, 6)
void leql_f32_kernel(const float* __restrict__ x,
                     const float* __restrict__ W0g, const float* __restrict__ b0g,
                     const float* __restrict__ W1g, const float* __restrict__ b1g,
                     const float* __restrict__ Wog, const float* __restrict__ bog,
                     float* __restrict__ out, int B)
{
    __shared__ float uf[32];
    __shared__ float WoS[1024];
    __shared__ float z0f[512], z1f[512];
    __shared__ float s0f[256], c0f[256], s1f[256], c1f[256];
    __shared__ float h1df[512];
    __shared__ float whatf[384];
    __shared__ float v0f[384];
    __shared__ float tmpf[512];          // also holds h0, then h1 (aliased)
    __shared__ float hd0f[384];
    __shared__ float zd1f[512];
    __shared__ float vd0f[384];
    __shared__ float Hf[32][17];
    __shared__ float yvf[2], ydf[2];
    __shared__ float Af[16][33], rf[16], qdo[16];
    __shared__ float wkc[16];
    __shared__ int ipiv[16];
    __shared__ int pivS;

    const int t = threadIdx.x;
    const int s = blockIdx.x;

    if (t < 32) uf[t] = x[s*32 + t];
    WoS[t] = Wog[t]; WoS[512+t] = Wog[512+t];
    __syncthreads();

    // ---- forward ----
    {
        const float* wr = &W0g[(128+t)*32];
        float acc = 0.0f;
        for (int c = 0; c < 32; ++c) acc = fmaf(wr[c], uf[c], acc);
        z0f[t] = __fadd_rn(acc, b0g[128+t]);
    }
    __syncthreads();
    if (t < 256) { s0f[t] = sinf(z0f[t]); c0f[t] = cosf(z0f[t]); }
    __syncthreads();
    if (t < 128)      tmpf[t] = 1.0f;                          // h0
    else if (t < 256) tmpf[t] = s0f[t-128];
    else if (t < 384) tmpf[t] = c0f[t-128];
    else              tmpf[t] = __fmul_rn(z0f[t-128], z0f[t]);
    __syncthreads();
    {
        const float* wr = &W1g[(size_t)(128+t)*512];
        float acc = 0.0f;
        for (int m = 0; m < 512; ++m) acc = fmaf(wr[m], tmpf[m], acc);
        z1f[t] = __fadd_rn(acc, b1g[128+t]);
    }
    __syncthreads();
    if (t < 256) { s1f[t] = sinf(z1f[t]); c1f[t] = cosf(z1f[t]); }
    __syncthreads();
    if (t < 128)      tmpf[t] = 1.0f;                          // h1
    else if (t < 256) tmpf[t] = s1f[t-128];
    else if (t < 384) tmpf[t] = c1f[t-128];
    else              tmpf[t] = __fmul_rn(z1f[t-128], z1f[t]);
    __syncthreads();
    if (t < 2) {
        float acc = 0.0f;
        for (int n = 0; n < 512; ++n) acc = fmaf(WoS[t*512 + n], tmpf[n], acc);
        yvf[t] = __fadd_rn(acc, bog[t]);
    }
    __syncthreads();

    // ---- quotient-rule seeds, jax-lax form ----
    const float y1 = yvf[0], y2 = yvf[1];

    // theta-gate early exit: for y2 <= 0.5 the reference where() zeroes the
    // cotangent exactly (jcob = h1 = h2 = 0), so qdd = inv(eps I) @ 0 = 0 and
    // lg = 0 -- identical to what the original kernel wrote for these samples.
    if (!(y2 > 0.5f)) {
        if (t < 16)  out[s*16 + t] = 0.0f;
        if (t == 16) out[(size_t)B*16 + s] = 0.0f;
        if (t == 17) out[(size_t)B*17 + s] = y2;
        return;
    }

    const float y2sq = __fmul_rn(y2, y2);
    const float r2 = 1.0f / y2sq;                       // integer_pow(y2,-2)
    const float r3 = 1.0f / __fmul_rn(y2sq, y2);        // integer_pow(y2,-3)
    const float sd1f = 1.0f / y2;                       // div VJP wrt numerator
    const float sd2f = __fmul_rn(-y1, r2);              // mul(mul(neg(ct),y1),y2^-2)

    // ---- base reverse pass ----
    if (t < 384) {                                       // Wo^T @ seed: fmaf k-chain
        float acc = fmaf(WoS[128+t], sd1f, 0.0f);
        whatf[t] = fmaf(WoS[512+128+t], sd2f, acc);
    }
    __syncthreads();
    {
        float v;
        if (t < 128)      v =  __fmul_rn(whatf[t],     c1f[t]);
        else if (t < 256) v = -__fmul_rn(whatf[t],     s1f[t]);
        else if (t < 384) v =  __fmul_rn(whatf[t],     z1f[t+128]);
        else              v =  __fmul_rn(whatf[t-128], z1f[t-128]);
        tmpf[t] = v;
    }
    __syncthreads();
    if (t < 384) {
        const float* wc = &W1g[(size_t)128*512 + 128 + t];
        float acc = 0.0f;
        for (int p = 0; p < 512; ++p) acc = fmaf(tmpf[p], wc[(size_t)p*512], acc);
        v0f[t] = acc;
    }
    __syncthreads();
    {
        float v;
        if (t < 128)      v =  __fmul_rn(v0f[t],     c0f[t]);
        else if (t < 256) v = -__fmul_rn(v0f[t],     s0f[t]);
        else if (t < 384) v =  __fmul_rn(v0f[t],     z0f[t+128]);
        else              v =  __fmul_rn(v0f[t-128], z0f[t-128]);
        tmpf[t] = v;
    }
    __syncthreads();
    if (t < 32) {
        float acc = 0.0f;
        for (int p = 0; p < 512; ++p) acc = fmaf(tmpf[p], W0g[(128+p)*32 + t], acc);
        Hf[t][16] = acc;
    }
    __syncthreads();

    // ---- 16 tangent passes ----
    for (int j = 0; j < 16; ++j) {
        const int cj = 16 + j;
        if (t < 384) {
            float v;
            if (t < 128)      v =  __fmul_rn(c0f[t], W0g[(128+t)*32 + cj]);
            else if (t < 256) v = -__fmul_rn(s0f[t], W0g[(128+t)*32 + cj]);
            else {
                int i = t - 256;
                v = __fadd_rn(__fmul_rn(W0g[(384+i)*32 + cj], z0f[384+i]),
                              __fmul_rn(z0f[256+i], W0g[(512+i)*32 + cj]));
            }
            hd0f[t] = v;
        }
        __syncthreads();
        {
            const float* wr = &W1g[(size_t)(128+t)*512 + 128];
            float acc = 0.0f;
            for (int m = 0; m < 384; ++m) acc = fmaf(wr[m], hd0f[m], acc);
            zd1f[t] = acc;
        }
        __syncthreads();
        {
            float v;
            if (t < 128)      v = 0.0f;
            else if (t < 256) v =  __fmul_rn(c1f[t-128], zd1f[t-128]);
            else if (t < 384) v = -__fmul_rn(s1f[t-128], zd1f[t-128]);
            else              v = __fadd_rn(__fmul_rn(zd1f[t-128], z1f[t]),
                                            __fmul_rn(z1f[t-128], zd1f[t]));
            h1df[t] = v;
        }
        __syncthreads();
        if (t < 2) {
            float acc = 0.0f;
            for (int n = 0; n < 512; ++n) acc = fmaf(WoS[t*512 + n], h1df[n], acc);
            ydf[t] = acc;
        }
        __syncthreads();
        {   // vdot1, jax-JVP associations
            float yd1 = ydf[0], yd2 = ydf[1];
            float sdot1 = __fmul_rn(-yd2, r2);
            float dr2 = __fmul_rn(__fmul_rn(yd2, -2.0f), r3);
            float sdot2 = __fadd_rn(__fmul_rn(-yd1, r2), __fmul_rn(-y1, dr2));
            int n = (t < 384) ? (128 + t) : t;
            float wd = fmaf(WoS[512+n], sdot2, fmaf(WoS[n], sdot1, 0.0f));
            float v;
            if (t < 128) {                       // sin node: what*cos(z1)
                float dcs = __fmul_rn(zd1f[t], -s1f[t]);      // d(cos) = zd*(-sin)
                v = __fadd_rn(__fmul_rn(wd, c1f[t]), __fmul_rn(whatf[t], dcs));
            } else if (t < 256) {                // cos node: what*(-sin(z1))
                float dsn = __fmul_rn(zd1f[t], c1f[t]);       // d(sin) = zd*cos
                v = __fadd_rn(__fmul_rn(wd, -s1f[t]), __fmul_rn(whatf[t], -dsn));
            } else if (t < 384) {
                v = __fadd_rn(__fmul_rn(wd, z1f[t+128]),
                              __fmul_rn(whatf[t], zd1f[t+128]));
            } else {
                v = __fadd_rn(__fmul_rn(wd, z1f[t-128]),
                              __fmul_rn(whatf[t-128], zd1f[t-128]));
            }
            tmpf[t] = v;
        }
        __syncthreads();
        if (t < 384) {
            const float* wc = &W1g[(size_t)128*512 + 128 + t];
            float acc = 0.0f;
            for (int p = 0; p < 512; ++p) acc = fmaf(tmpf[p], wc[(size_t)p*512], acc);
            vd0f[t] = acc;
        }
        __syncthreads();
        {   // dzdot0, jax-JVP associations
            float v;
            if (t < 128) {                       // sin z0 node: v0*cos(z0)
                float e = W0g[(128+t)*32 + cj];
                float dcs = __fmul_rn(e, -s0f[t]);
                v = __fadd_rn(__fmul_rn(vd0f[t], c0f[t]), __fmul_rn(v0f[t], dcs));
            } else if (t < 256) {                // cos z0 node: v0*(-sin(z0))
                float e = W0g[(128+t)*32 + cj];
                float dsn = __fmul_rn(e, c0f[t]);
                v = __fadd_rn(__fmul_rn(vd0f[t], -s0f[t]), __fmul_rn(v0f[t], -dsn));
            } else if (t < 384) {
                float eb = W0g[(256+t)*32 + cj];
                v = __fadd_rn(__fmul_rn(vd0f[t], z0f[t+128]), __fmul_rn(v0f[t], eb));
            } else {
                float ea = W0g[t*32 + cj];
                v = __fadd_rn(__fmul_rn(vd0f[t-128], z0f[t-128]), __fmul_rn(v0f[t-128], ea));
            }
            tmpf[t] = v;
        }
        __syncthreads();
        if (t < 32) {
            float acc = 0.0f;
            for (int p = 0; p < 512; ++p) acc = fmaf(tmpf[p], W0g[(128+p)*32 + t], acc);
            Hf[t][j] = acc;
        }
        __syncthreads();
    }

    // ---- A = h1 + eps I; rhs = jcob - h2@q ----
    if (t < 256) {
        int i = t >> 4, jj = t & 15;
        Af[i][jj] = (i == jj) ? __fadd_rn(Hf[16+i][jj], 1.0e-3f) : Hf[16+i][jj];
    }
    if (t >= 256 && t < 272) {
        int i = t - 256;
        float dd = 0.0f;
        for (int jj = 0; jj < 16; ++jj) dd = fmaf(Hf[i][jj], uf[jj], dd);
        rf[i] = __fsub_rn(Hf[i][16], dd);
    }
    __syncthreads();

    // sgetf2
    for (int j = 0; j < 16; ++j) {
        if (t == 0) {
            int p = j; float best = fabsf(Af[j][j]);
            for (int r = j+1; r < 16; ++r) {
                float v = fabsf(Af[r][j]);
                if (v > best) { best = v; p = r; }
            }
            ipiv[j] = p; pivS = p;
        }
        __syncthreads();
        int piv = pivS;
        if (piv != j && t < 16) {
            float tv = Af[j][t]; Af[j][t] = Af[piv][t]; Af[piv][t] = tv;
        }
        __syncthreads();
        float recip = 1.0f / Af[j][j];
        if (t > j && t < 16) Af[t][j] = __fmul_rn(Af[t][j], recip);
        __syncthreads();
        if (t < 256) {
            int i = t >> 4, k = t & 15;
            if (i > j && k > j) Af[i][k] = fmaf(-Af[i][j], Af[j][k], Af[i][k]);
        }
        __syncthreads();
    }

    // sgetri: strti2 + descending-j sweep + reverse column pivots
    if (t == 0) {
        for (int j = 0; j < 16; ++j) {
            float ajj_inv = 1.0f / Af[j][j];
            Af[j][j] = ajj_inv;
            float ajj = -ajj_inv;
            for (int j2 = 0; j2 < j; ++j2) {
                float temp = Af[j2][j];
                if (temp != 0.0f)
                    for (int i = 0; i < j2; ++i)
                        Af[i][j] = fmaf(temp, Af[i][j2], Af[i][j]);
                Af[j2][j] = __fmul_rn(Af[j2][j], Af[j2][j2]);
            }
            for (int i = 0; i < j; ++i) Af[i][j] = __fmul_rn(Af[i][j], ajj);
        }
    }
    __syncthreads();
    for (int j = 15; j >= 0; --j) {
        if (t > j && t < 16) { wkc[t] = Af[t][j]; Af[t][j] = 0.0f; }
        __syncthreads();
        if (t < 16) {
            float acc = Af[t][j];
            for (int k = j+1; k < 16; ++k) acc = fmaf(-wkc[k], Af[t][k], acc);
            Af[t][j] = acc;
        }
        __syncthreads();
    }
    if (t < 16) {
        for (int j = 15; j >= 0; --j) {
            int jp = ipiv[j];
            if (jp != j) { float tv = Af[t][j]; Af[t][j] = Af[t][jp]; Af[t][jp] = tv; }
        }
    }
    __syncthreads();

    // qdd = inv @ rhs
    if (t < 16) {
        float acc = 0.0f;
        for (int jj = 0; jj < 16; ++jj) acc = fmaf(Af[t][jj], rf[jj], acc);
        qdo[t] = acc;
    }
    __syncthreads();

    // ---- outputs (gate is true on this path) ----
    if (t < 16)  out[s*16 + t] = qdo[t];
    if (t == 16) out[(size_t)B*16 + s] = y1 / y2;
    if (t == 17) out[(size_t)B*17 + s] = y2;
}

extern "C" void kernel_launch(void* const* d_in, const int* in_sizes, int n_in,
                              void* d_out, int out_size, void* d_ws, size_t ws_size,
                              hipStream_t stream) {
    (void)n_in; (void)out_size; (void)d_ws; (void)ws_size;
    const float* x  = (const float*)d_in[0];
    const float* W0 = (const float*)d_in[1];
    const float* b0 = (const float*)d_in[2];
    const float* W1 = (const float*)d_in[3];
    const float* b1 = (const float*)d_in[4];
    const float* Wo = (const float*)d_in[5];
    const float* bo = (const float*)d_in[6];
    const int B = in_sizes[0] / 32;
    hipLaunchKernelGGL(leql_f32_kernel, dim3(B), dim3(512), 0, stream,
                       x, W0, b0, W1, b1, Wo, bo, (float*)d_out, B);
}

// Round 6
// 1943.800 us; speedup vs baseline: 1.6905x; 1.0144x over previous
//
#include <hip/hip_runtime.h>
#include <cmath>

// One workgroup (512 threads) per sample.
// VERBATIM the R5 passing kernel (absmax 4096, 1972us) with ONE mechanism change:
//   the two row-pattern W1 GEMVs (forward z1, tangent zd1) load W1 via float4
//   (16B per issue, ascending unpack, single accumulator -> bit-identical fmaf
//   association). These are the uncoalesced-across-lanes stages (lane stride
//   2KB): 4x fewer load issues, 4x better cache-line economy.
__global__ __launch_bounds__(512, 6)
void leql_f32_kernel(const float* __restrict__ x,
                     const float* __restrict__ W0g, const float* __restrict__ b0g,
                     const float* __restrict__ W1g, const float* __restrict__ b1g,
                     const float* __restrict__ Wog, const float* __restrict__ bog,
                     float* __restrict__ out, int B)
{
    __shared__ float uf[32];
    __shared__ float WoS[1024];
    __shared__ float z0f[512], z1f[512];
    __shared__ float s0f[256], c0f[256], s1f[256], c1f[256];
    __shared__ float h1df[512];
    __shared__ float whatf[384];
    __shared__ float v0f[384];
    __shared__ float tmpf[512];          // also holds h0, then h1 (aliased)
    __shared__ float hd0f[384];
    __shared__ float zd1f[512];
    __shared__ float vd0f[384];
    __shared__ float Hf[32][17];
    __shared__ float yvf[2], ydf[2];
    __shared__ float Af[16][33], rf[16], qdo[16];
    __shared__ float wkc[16];
    __shared__ int ipiv[16];
    __shared__ int pivS;

    const int t = threadIdx.x;
    const int s = blockIdx.x;

    if (t < 32) uf[t] = x[s*32 + t];
    WoS[t] = Wog[t]; WoS[512+t] = Wog[512+t];
    __syncthreads();

    // ---- forward ----
    {
        const float* wr = &W0g[(128+t)*32];
        float acc = 0.0f;
        for (int c = 0; c < 32; ++c) acc = fmaf(wr[c], uf[c], acc);
        z0f[t] = __fadd_rn(acc, b0g[128+t]);
    }
    __syncthreads();
    if (t < 256) { s0f[t] = sinf(z0f[t]); c0f[t] = cosf(z0f[t]); }
    __syncthreads();
    if (t < 128)      tmpf[t] = 1.0f;                          // h0
    else if (t < 256) tmpf[t] = s0f[t-128];
    else if (t < 384) tmpf[t] = c0f[t-128];
    else              tmpf[t] = __fmul_rn(z0f[t-128], z0f[t]);
    __syncthreads();
    {
        // row-pattern W1 GEMV: float4 loads, ascending unpack (bit-identical)
        const float* wr = &W1g[(size_t)(128+t)*512];
        float acc = 0.0f;
        for (int m = 0; m < 512; m += 4) {
            const float4 w = *(const float4*)(wr + m);
            acc = fmaf(w.x, tmpf[m+0], acc);
            acc = fmaf(w.y, tmpf[m+1], acc);
            acc = fmaf(w.z, tmpf[m+2], acc);
            acc = fmaf(w.w, tmpf[m+3], acc);
        }
        z1f[t] = __fadd_rn(acc, b1g[128+t]);
    }
    __syncthreads();
    if (t < 256) { s1f[t] = sinf(z1f[t]); c1f[t] = cosf(z1f[t]); }
    __syncthreads();
    if (t < 128)      tmpf[t] = 1.0f;                          // h1
    else if (t < 256) tmpf[t] = s1f[t-128];
    else if (t < 384) tmpf[t] = c1f[t-128];
    else              tmpf[t] = __fmul_rn(z1f[t-128], z1f[t]);
    __syncthreads();
    if (t < 2) {
        float acc = 0.0f;
        for (int n = 0; n < 512; ++n) acc = fmaf(WoS[t*512 + n], tmpf[n], acc);
        yvf[t] = __fadd_rn(acc, bog[t]);
    }
    __syncthreads();

    // ---- quotient-rule seeds, jax-lax form ----
    const float y1 = yvf[0], y2 = yvf[1];

    // theta-gate early exit: for y2 <= 0.5 the reference where() zeroes the
    // cotangent exactly (jcob = h1 = h2 = 0), so qdd = inv(eps I) @ 0 = 0 and
    // lg = 0 -- identical to what the original kernel wrote for these samples.
    if (!(y2 > 0.5f)) {
        if (t < 16)  out[s*16 + t] = 0.0f;
        if (t == 16) out[(size_t)B*16 + s] = 0.0f;
        if (t == 17) out[(size_t)B*17 + s] = y2;
        return;
    }

    const float y2sq = __fmul_rn(y2, y2);
    const float r2 = 1.0f / y2sq;                       // integer_pow(y2,-2)
    const float r3 = 1.0f / __fmul_rn(y2sq, y2);        // integer_pow(y2,-3)
    const float sd1f = 1.0f / y2;                       // div VJP wrt numerator
    const float sd2f = __fmul_rn(-y1, r2);              // mul(mul(neg(ct),y1),y2^-2)

    // ---- base reverse pass ----
    if (t < 384) {                                       // Wo^T @ seed: fmaf k-chain
        float acc = fmaf(WoS[128+t], sd1f, 0.0f);
        whatf[t] = fmaf(WoS[512+128+t], sd2f, acc);
    }
    __syncthreads();
    {
        float v;
        if (t < 128)      v =  __fmul_rn(whatf[t],     c1f[t]);
        else if (t < 256) v = -__fmul_rn(whatf[t],     s1f[t]);
        else if (t < 384) v =  __fmul_rn(whatf[t],     z1f[t+128]);
        else              v =  __fmul_rn(whatf[t-128], z1f[t-128]);
        tmpf[t] = v;
    }
    __syncthreads();
    if (t < 384) {
        const float* wc = &W1g[(size_t)128*512 + 128 + t];
        float acc = 0.0f;
        for (int p = 0; p < 512; ++p) acc = fmaf(tmpf[p], wc[(size_t)p*512], acc);
        v0f[t] = acc;
    }
    __syncthreads();
    {
        float v;
        if (t < 128)      v =  __fmul_rn(v0f[t],     c0f[t]);
        else if (t < 256) v = -__fmul_rn(v0f[t],     s0f[t]);
        else if (t < 384) v =  __fmul_rn(v0f[t],     z0f[t+128]);
        else              v =  __fmul_rn(v0f[t-128], z0f[t-128]);
        tmpf[t] = v;
    }
    __syncthreads();
    if (t < 32) {
        float acc = 0.0f;
        for (int p = 0; p < 512; ++p) acc = fmaf(tmpf[p], W0g[(128+p)*32 + t], acc);
        Hf[t][16] = acc;
    }
    __syncthreads();

    // ---- 16 tangent passes ----
    for (int j = 0; j < 16; ++j) {
        const int cj = 16 + j;
        if (t < 384) {
            float v;
            if (t < 128)      v =  __fmul_rn(c0f[t], W0g[(128+t)*32 + cj]);
            else if (t < 256) v = -__fmul_rn(s0f[t], W0g[(128+t)*32 + cj]);
            else {
                int i = t - 256;
                v = __fadd_rn(__fmul_rn(W0g[(384+i)*32 + cj], z0f[384+i]),
                              __fmul_rn(z0f[256+i], W0g[(512+i)*32 + cj]));
            }
            hd0f[t] = v;
        }
        __syncthreads();
        {
            // row-pattern W1 GEMV: float4 loads, ascending unpack (bit-identical)
            const float* wr = &W1g[(size_t)(128+t)*512 + 128];
            float acc = 0.0f;
            for (int m = 0; m < 384; m += 4) {
                const float4 w = *(const float4*)(wr + m);
                acc = fmaf(w.x, hd0f[m+0], acc);
                acc = fmaf(w.y, hd0f[m+1], acc);
                acc = fmaf(w.z, hd0f[m+2], acc);
                acc = fmaf(w.w, hd0f[m+3], acc);
            }
            zd1f[t] = acc;
        }
        __syncthreads();
        {
            float v;
            if (t < 128)      v = 0.0f;
            else if (t < 256) v =  __fmul_rn(c1f[t-128], zd1f[t-128]);
            else if (t < 384) v = -__fmul_rn(s1f[t-128], zd1f[t-128]);
            else              v = __fadd_rn(__fmul_rn(zd1f[t-128], z1f[t]),
                                            __fmul_rn(z1f[t-128], zd1f[t]));
            h1df[t] = v;
        }
        __syncthreads();
        if (t < 2) {
            float acc = 0.0f;
            for (int n = 0; n < 512; ++n) acc = fmaf(WoS[t*512 + n], h1df[n], acc);
            ydf[t] = acc;
        }
        __syncthreads();
        {   // vdot1, jax-JVP associations
            float yd1 = ydf[0], yd2 = ydf[1];
            float sdot1 = __fmul_rn(-yd2, r2);
            float dr2 = __fmul_rn(__fmul_rn(yd2, -2.0f), r3);
            float sdot2 = __fadd_rn(__fmul_rn(-yd1, r2), __fmul_rn(-y1, dr2));
            int n = (t < 384) ? (128 + t) : t;
            float wd = fmaf(WoS[512+n], sdot2, fmaf(WoS[n], sdot1, 0.0f));
            float v;
            if (t < 128) {                       // sin node: what*cos(z1)
                float dcs = __fmul_rn(zd1f[t], -s1f[t]);      // d(cos) = zd*(-sin)
                v = __fadd_rn(__fmul_rn(wd, c1f[t]), __fmul_rn(whatf[t], dcs));
            } else if (t < 256) {                // cos node: what*(-sin(z1))
                float dsn = __fmul_rn(zd1f[t], c1f[t]);       // d(sin) = zd*cos
                v = __fadd_rn(__fmul_rn(wd, -s1f[t]), __fmul_rn(whatf[t], -dsn));
            } else if (t < 384) {
                v = __fadd_rn(__fmul_rn(wd, z1f[t+128]),
                              __fmul_rn(whatf[t], zd1f[t+128]));
            } else {
                v = __fadd_rn(__fmul_rn(wd, z1f[t-128]),
                              __fmul_rn(whatf[t-128], zd1f[t-128]));
            }
            tmpf[t] = v;
        }
        __syncthreads();
        if (t < 384) {
            const float* wc = &W1g[(size_t)128*512 + 128 + t];
            float acc = 0.0f;
            for (int p = 0; p < 512; ++p) acc = fmaf(tmpf[p], wc[(size_t)p*512], acc);
            vd0f[t] = acc;
        }
        __syncthreads();
        {   // dzdot0, jax-JVP associations
            float v;
            if (t < 128) {                       // sin z0 node: v0*cos(z0)
                float e = W0g[(128+t)*32 + cj];
                float dcs = __fmul_rn(e, -s0f[t]);
                v = __fadd_rn(__fmul_rn(vd0f[t], c0f[t]), __fmul_rn(v0f[t], dcs));
            } else if (t < 256) {                // cos z0 node: v0*(-sin(z0))
                float e = W0g[(128+t)*32 + cj];
                float dsn = __fmul_rn(e, c0f[t]);
                v = __fadd_rn(__fmul_rn(vd0f[t], -s0f[t]), __fmul_rn(v0f[t], -dsn));
            } else if (t < 384) {
                float eb = W0g[(256+t)*32 + cj];
                v = __fadd_rn(__fmul_rn(vd0f[t], z0f[t+128]), __fmul_rn(v0f[t], eb));
            } else {
                float ea = W0g[t*32 + cj];
                v = __fadd_rn(__fmul_rn(vd0f[t-128], z0f[t-128]), __fmul_rn(v0f[t-128], ea));
            }
            tmpf[t] = v;
        }
        __syncthreads();
        if (t < 32) {
            float acc = 0.0f;
            for (int p = 0; p < 512; ++p) acc = fmaf(tmpf[p], W0g[(128+p)*32 + t], acc);
            Hf[t][j] = acc;
        }
        __syncthreads();
    }

    // ---- A = h1 + eps I; rhs = jcob - h2@q ----
    if (t < 256) {
        int i = t >> 4, jj = t & 15;
        Af[i][jj] = (i == jj) ? __fadd_rn(Hf[16+i][jj], 1.0e-3f) : Hf[16+i][jj];
    }
    if (t >= 256 && t < 272) {
        int i = t - 256;
        float dd = 0.0f;
        for (int jj = 0; jj < 16; ++jj) dd = fmaf(Hf[i][jj], uf[jj], dd);
        rf[i] = __fsub_rn(Hf[i][16], dd);
    }
    __syncthreads();

    // sgetf2
    for (int j = 0; j < 16; ++j) {
        if (t == 0) {
            int p = j; float best = fabsf(Af[j][j]);
            for (int r = j+1; r < 16; ++r) {
                float v = fabsf(Af[r][j]);
                if (v > best) { best = v; p = r; }
            }
            ipiv[j] = p; pivS = p;
        }
        __syncthreads();
        int piv = pivS;
        if (piv != j && t < 16) {
            float tv = Af[j][t]; Af[j][t] = Af[piv][t]; Af[piv][t] = tv;
        }
        __syncthreads();
        float recip = 1.0f / Af[j][j];
        if (t > j && t < 16) Af[t][j] = __fmul_rn(Af[t][j], recip);
        __syncthreads();
        if (t < 256) {
            int i = t >> 4, k = t & 15;
            if (i > j && k > j) Af[i][k] = fmaf(-Af[i][j], Af[j][k], Af[i][k]);
        }
        __syncthreads();
    }

    // sgetri: strti2 + descending-j sweep + reverse column pivots
    if (t == 0) {
        for (int j = 0; j < 16; ++j) {
            float ajj_inv = 1.0f / Af[j][j];
            Af[j][j] = ajj_inv;
            float ajj = -ajj_inv;
            for (int j2 = 0; j2 < j; ++j2) {
                float temp = Af[j2][j];
                if (temp != 0.0f)
                    for (int i = 0; i < j2; ++i)
                        Af[i][j] = fmaf(temp, Af[i][j2], Af[i][j]);
                Af[j2][j] = __fmul_rn(Af[j2][j], Af[j2][j2]);
            }
            for (int i = 0; i < j; ++i) Af[i][j] = __fmul_rn(Af[i][j], ajj);
        }
    }
    __syncthreads();
    for (int j = 15; j >= 0; --j) {
        if (t > j && t < 16) { wkc[t] = Af[t][j]; Af[t][j] = 0.0f; }
        __syncthreads();
        if (t < 16) {
            float acc = Af[t][j];
            for (int k = j+1; k < 16; ++k) acc = fmaf(-wkc[k], Af[t][k], acc);
            Af[t][j] = acc;
        }
        __syncthreads();
    }
    if (t < 16) {
        for (int j = 15; j >= 0; --j) {
            int jp = ipiv[j];
            if (jp != j) { float tv = Af[t][j]; Af[t][j] = Af[t][jp]; Af[t][jp] = tv; }
        }
    }
    __syncthreads();

    // qdd = inv @ rhs
    if (t < 16) {
        float acc = 0.0f;
        for (int jj = 0; jj < 16; ++jj) acc = fmaf(Af[t][jj], rf[jj], acc);
        qdo[t] = acc;
    }
    __syncthreads();

    // ---- outputs (gate is true on this path) ----
    if (t < 16)  out[s*16 + t] = qdo[t];
    if (t == 16) out[(size_t)B*16 + s] = y1 / y2;
    if (t == 17) out[(size_t)B*17 + s] = y2;
}

extern "C" void kernel_launch(void* const* d_in, const int* in_sizes, int n_in,
                              void* d_out, int out_size, void* d_ws, size_t ws_size,
                              hipStream_t stream) {
    (void)n_in; (void)out_size; (void)d_ws; (void)ws_size;
    const float* x  = (const float*)d_in[0];
    const float* W0 = (const float*)d_in[1];
    const float* b0 = (const float*)d_in[2];
    const float* W1 = (const float*)d_in[3];
    const float* b1 = (const float*)d_in[4];
    const float* Wo = (const float*)d_in[5];
    const float* bo = (const float*)d_in[6];
    const int B = in_sizes[0] / 32;
    hipLaunchKernelGGL(leql_f32_kernel, dim3(B), dim3(512), 0, stream,
                       x, W0, b0, W1, b1, Wo, bo, (float*)d_out, B);
}

// Round 7
// 1931.680 us; speedup vs baseline: 1.7011x; 1.0063x over previous
//
#include <hip/hip_runtime.h>
#include <cmath>

// Transpose the used W1 panel: w1t[c][p] = W1[128+p][128+c], c<384, p<512.
// Same values, enables contiguous float4 reads for the column-pattern GEMVs.
__global__ void transpose_w1(const float* __restrict__ W1g, float* __restrict__ w1t) {
    int idx = blockIdx.x * 256 + threadIdx.x;
    if (idx < 384*512) {
        int c = idx >> 9;          // 0..383
        int p = idx & 511;         // 0..511
        w1t[idx] = W1g[(size_t)(128+p)*512 + 128 + c];
    }
}

// One workgroup (512 threads) per sample. Based on the R6 passing kernel
// (absmax 4096, 1944us). Two bit-exact mechanism changes:
//  1. zd1 tangent GEMV batched by 4 columns (4 independent ascending-m fmaf
//     chains per thread, same per-column association; W1 row-sweeps 16 -> 4).
//  2. column-pattern W1 GEMVs (v0f, vd0f) read the pre-transposed w1t panel
//     with float4 (same values, same ascending-p order; 512 -> 128 issues).
__global__ __launch_bounds__(512, 6)
void leql_f32_kernel(const float* __restrict__ x,
                     const float* __restrict__ W0g, const float* __restrict__ b0g,
                     const float* __restrict__ W1g, const float* __restrict__ b1g,
                     const float* __restrict__ Wog, const float* __restrict__ bog,
                     const float* __restrict__ w1t,
                     float* __restrict__ out, int B)
{
    __shared__ float uf[32];
    __shared__ float WoS[1024];
    __shared__ float z0f[512], z1f[512];
    __shared__ float s0f[256], c0f[256], s1f[256], c1f[256];
    __shared__ float h1df[512];
    __shared__ float whatf[384];
    __shared__ float v0f[384];
    __shared__ float tmpf[512];          // also holds h0, then h1 (aliased)
    __shared__ __align__(16) float hd0a[4][384];
    __shared__ float zd1a[4][512];
    __shared__ float vd0f[384];
    __shared__ float Hf[32][17];
    __shared__ float yvf[2], ydf[2];
    __shared__ float Af[16][33], rf[16], qdo[16];
    __shared__ float wkc[16];
    __shared__ int ipiv[16];
    __shared__ int pivS;

    const int t = threadIdx.x;
    const int s = blockIdx.x;

    if (t < 32) uf[t] = x[s*32 + t];
    WoS[t] = Wog[t]; WoS[512+t] = Wog[512+t];
    __syncthreads();

    // ---- forward ----
    {
        const float* wr = &W0g[(128+t)*32];
        float acc = 0.0f;
        for (int c = 0; c < 32; ++c) acc = fmaf(wr[c], uf[c], acc);
        z0f[t] = __fadd_rn(acc, b0g[128+t]);
    }
    __syncthreads();
    if (t < 256) { s0f[t] = sinf(z0f[t]); c0f[t] = cosf(z0f[t]); }
    __syncthreads();
    if (t < 128)      tmpf[t] = 1.0f;                          // h0
    else if (t < 256) tmpf[t] = s0f[t-128];
    else if (t < 384) tmpf[t] = c0f[t-128];
    else              tmpf[t] = __fmul_rn(z0f[t-128], z0f[t]);
    __syncthreads();
    {
        const float* wr = &W1g[(size_t)(128+t)*512];
        float acc = 0.0f;
        for (int m = 0; m < 512; m += 4) {
            const float4 w = *(const float4*)(wr + m);
            acc = fmaf(w.x, tmpf[m+0], acc);
            acc = fmaf(w.y, tmpf[m+1], acc);
            acc = fmaf(w.z, tmpf[m+2], acc);
            acc = fmaf(w.w, tmpf[m+3], acc);
        }
        z1f[t] = __fadd_rn(acc, b1g[128+t]);
    }
    __syncthreads();
    if (t < 256) { s1f[t] = sinf(z1f[t]); c1f[t] = cosf(z1f[t]); }
    __syncthreads();
    if (t < 128)      tmpf[t] = 1.0f;                          // h1
    else if (t < 256) tmpf[t] = s1f[t-128];
    else if (t < 384) tmpf[t] = c1f[t-128];
    else              tmpf[t] = __fmul_rn(z1f[t-128], z1f[t]);
    __syncthreads();
    if (t < 2) {
        float acc = 0.0f;
        for (int n = 0; n < 512; ++n) acc = fmaf(WoS[t*512 + n], tmpf[n], acc);
        yvf[t] = __fadd_rn(acc, bog[t]);
    }
    __syncthreads();

    // ---- quotient-rule seeds, jax-lax form ----
    const float y1 = yvf[0], y2 = yvf[1];

    // theta-gate early exit (bit-exact: reference where() zeroes jcob/h1/h2)
    if (!(y2 > 0.5f)) {
        if (t < 16)  out[s*16 + t] = 0.0f;
        if (t == 16) out[(size_t)B*16 + s] = 0.0f;
        if (t == 17) out[(size_t)B*17 + s] = y2;
        return;
    }

    const float y2sq = __fmul_rn(y2, y2);
    const float r2 = 1.0f / y2sq;                       // integer_pow(y2,-2)
    const float r3 = 1.0f / __fmul_rn(y2sq, y2);        // integer_pow(y2,-3)
    const float sd1f = 1.0f / y2;                       // div VJP wrt numerator
    const float sd2f = __fmul_rn(-y1, r2);              // mul(mul(neg(ct),y1),y2^-2)

    // ---- base reverse pass ----
    if (t < 384) {                                       // Wo^T @ seed: fmaf k-chain
        float acc = fmaf(WoS[128+t], sd1f, 0.0f);
        whatf[t] = fmaf(WoS[512+128+t], sd2f, acc);
    }
    __syncthreads();
    {
        float v;
        if (t < 128)      v =  __fmul_rn(whatf[t],     c1f[t]);
        else if (t < 256) v = -__fmul_rn(whatf[t],     s1f[t]);
        else if (t < 384) v =  __fmul_rn(whatf[t],     z1f[t+128]);
        else              v =  __fmul_rn(whatf[t-128], z1f[t-128]);
        tmpf[t] = v;
    }
    __syncthreads();
    if (t < 384) {
        float acc = 0.0f;
        if (w1t) {
            const float* wr = &w1t[(size_t)t*512];
            for (int p = 0; p < 512; p += 4) {
                const float4 w = *(const float4*)(wr + p);
                acc = fmaf(tmpf[p+0], w.x, acc);
                acc = fmaf(tmpf[p+1], w.y, acc);
                acc = fmaf(tmpf[p+2], w.z, acc);
                acc = fmaf(tmpf[p+3], w.w, acc);
            }
        } else {
            const float* wc = &W1g[(size_t)128*512 + 128 + t];
            for (int p = 0; p < 512; ++p) acc = fmaf(tmpf[p], wc[(size_t)p*512], acc);
        }
        v0f[t] = acc;
    }
    __syncthreads();
    {
        float v;
        if (t < 128)      v =  __fmul_rn(v0f[t],     c0f[t]);
        else if (t < 256) v = -__fmul_rn(v0f[t],     s0f[t]);
        else if (t < 384) v =  __fmul_rn(v0f[t],     z0f[t+128]);
        else              v =  __fmul_rn(v0f[t-128], z0f[t-128]);
        tmpf[t] = v;
    }
    __syncthreads();
    if (t < 32) {
        float acc = 0.0f;
        for (int p = 0; p < 512; ++p) acc = fmaf(tmpf[p], W0g[(128+p)*32 + t], acc);
        Hf[t][16] = acc;
    }
    __syncthreads();

    // ---- 16 tangent passes: 4 groups of 4 batched columns ----
    for (int g = 0; g < 4; ++g) {
        const int cj0 = 16 + g*4;

        // hd0 for 4 columns (per-column scalar formulas verbatim)
        if (t < 384) {
            if (t < 128) {
                const float4 e = *(const float4*)&W0g[(128+t)*32 + cj0];
                const float cth = c0f[t];
                hd0a[0][t] = __fmul_rn(cth, e.x);
                hd0a[1][t] = __fmul_rn(cth, e.y);
                hd0a[2][t] = __fmul_rn(cth, e.z);
                hd0a[3][t] = __fmul_rn(cth, e.w);
            } else if (t < 256) {
                const float4 e = *(const float4*)&W0g[(128+t)*32 + cj0];
                const float sth = s0f[t];
                hd0a[0][t] = -__fmul_rn(sth, e.x);
                hd0a[1][t] = -__fmul_rn(sth, e.y);
                hd0a[2][t] = -__fmul_rn(sth, e.z);
                hd0a[3][t] = -__fmul_rn(sth, e.w);
            } else {
                const int i = t - 256;
                const float4 p4 = *(const float4*)&W0g[(384+i)*32 + cj0];
                const float4 q4 = *(const float4*)&W0g[(512+i)*32 + cj0];
                const float za = z0f[384+i], zb = z0f[256+i];
                hd0a[0][t] = __fadd_rn(__fmul_rn(p4.x, za), __fmul_rn(zb, q4.x));
                hd0a[1][t] = __fadd_rn(__fmul_rn(p4.y, za), __fmul_rn(zb, q4.y));
                hd0a[2][t] = __fadd_rn(__fmul_rn(p4.z, za), __fmul_rn(zb, q4.z));
                hd0a[3][t] = __fadd_rn(__fmul_rn(p4.w, za), __fmul_rn(zb, q4.w));
            }
        }
        __syncthreads();

        // zd1 for 4 columns: ONE W1-row sweep, 4 independent ascending chains
        {
            const float* wr = &W1g[(size_t)(128+t)*512 + 128];
            float a0=0.0f, a1=0.0f, a2=0.0f, a3=0.0f;
            for (int m = 0; m < 384; m += 4) {
                const float4 w  = *(const float4*)(wr + m);
                const float4 h0 = *(const float4*)&hd0a[0][m];
                const float4 h1 = *(const float4*)&hd0a[1][m];
                const float4 h2 = *(const float4*)&hd0a[2][m];
                const float4 h3 = *(const float4*)&hd0a[3][m];
                a0 = fmaf(w.x, h0.x, a0); a0 = fmaf(w.y, h0.y, a0);
                a0 = fmaf(w.z, h0.z, a0); a0 = fmaf(w.w, h0.w, a0);
                a1 = fmaf(w.x, h1.x, a1); a1 = fmaf(w.y, h1.y, a1);
                a1 = fmaf(w.z, h1.z, a1); a1 = fmaf(w.w, h1.w, a1);
                a2 = fmaf(w.x, h2.x, a2); a2 = fmaf(w.y, h2.y, a2);
                a2 = fmaf(w.z, h2.z, a2); a2 = fmaf(w.w, h2.w, a2);
                a3 = fmaf(w.x, h3.x, a3); a3 = fmaf(w.y, h3.y, a3);
                a3 = fmaf(w.z, h3.z, a3); a3 = fmaf(w.w, h3.w, a3);
            }
            zd1a[0][t]=a0; zd1a[1][t]=a1; zd1a[2][t]=a2; zd1a[3][t]=a3;
        }
        __syncthreads();

        for (int jj = 0; jj < 4; ++jj) {
            const int j = g*4 + jj;
            const int cj = 16 + j;
            const float* zd1f = zd1a[jj];      // per-j view, code below verbatim
            {
                float v;
                if (t < 128)      v = 0.0f;
                else if (t < 256) v =  __fmul_rn(c1f[t-128], zd1f[t-128]);
                else if (t < 384) v = -__fmul_rn(s1f[t-128], zd1f[t-128]);
                else              v = __fadd_rn(__fmul_rn(zd1f[t-128], z1f[t]),
                                                __fmul_rn(z1f[t-128], zd1f[t]));
                h1df[t] = v;
            }
            __syncthreads();
            if (t < 2) {
                float acc = 0.0f;
                for (int n = 0; n < 512; ++n) acc = fmaf(WoS[t*512 + n], h1df[n], acc);
                ydf[t] = acc;
            }
            __syncthreads();
            {   // vdot1, jax-JVP associations
                float yd1 = ydf[0], yd2 = ydf[1];
                float sdot1 = __fmul_rn(-yd2, r2);
                float dr2 = __fmul_rn(__fmul_rn(yd2, -2.0f), r3);
                float sdot2 = __fadd_rn(__fmul_rn(-yd1, r2), __fmul_rn(-y1, dr2));
                int n = (t < 384) ? (128 + t) : t;
                float wd = fmaf(WoS[512+n], sdot2, fmaf(WoS[n], sdot1, 0.0f));
                float v;
                if (t < 128) {                       // sin node: what*cos(z1)
                    float dcs = __fmul_rn(zd1f[t], -s1f[t]);
                    v = __fadd_rn(__fmul_rn(wd, c1f[t]), __fmul_rn(whatf[t], dcs));
                } else if (t < 256) {                // cos node: what*(-sin(z1))
                    float dsn = __fmul_rn(zd1f[t], c1f[t]);
                    v = __fadd_rn(__fmul_rn(wd, -s1f[t]), __fmul_rn(whatf[t], -dsn));
                } else if (t < 384) {
                    v = __fadd_rn(__fmul_rn(wd, z1f[t+128]),
                                  __fmul_rn(whatf[t], zd1f[t+128]));
                } else {
                    v = __fadd_rn(__fmul_rn(wd, z1f[t-128]),
                                  __fmul_rn(whatf[t-128], zd1f[t-128]));
                }
                tmpf[t] = v;
            }
            __syncthreads();
            if (t < 384) {
                float acc = 0.0f;
                if (w1t) {
                    const float* wr2 = &w1t[(size_t)t*512];
                    for (int p = 0; p < 512; p += 4) {
                        const float4 w = *(const float4*)(wr2 + p);
                        acc = fmaf(tmpf[p+0], w.x, acc);
                        acc = fmaf(tmpf[p+1], w.y, acc);
                        acc = fmaf(tmpf[p+2], w.z, acc);
                        acc = fmaf(tmpf[p+3], w.w, acc);
                    }
                } else {
                    const float* wc = &W1g[(size_t)128*512 + 128 + t];
                    for (int p = 0; p < 512; ++p) acc = fmaf(tmpf[p], wc[(size_t)p*512], acc);
                }
                vd0f[t] = acc;
            }
            __syncthreads();
            {   // dzdot0, jax-JVP associations
                float v;
                if (t < 128) {                       // sin z0 node: v0*cos(z0)
                    float e = W0g[(128+t)*32 + cj];
                    float dcs = __fmul_rn(e, -s0f[t]);
                    v = __fadd_rn(__fmul_rn(vd0f[t], c0f[t]), __fmul_rn(v0f[t], dcs));
                } else if (t < 256) {                // cos z0 node: v0*(-sin(z0))
                    float e = W0g[(128+t)*32 + cj];
                    float dsn = __fmul_rn(e, c0f[t]);
                    v = __fadd_rn(__fmul_rn(vd0f[t], -s0f[t]), __fmul_rn(v0f[t], -dsn));
                } else if (t < 384) {
                    float eb = W0g[(256+t)*32 + cj];
                    v = __fadd_rn(__fmul_rn(vd0f[t], z0f[t+128]), __fmul_rn(v0f[t], eb));
                } else {
                    float ea = W0g[t*32 + cj];
                    v = __fadd_rn(__fmul_rn(vd0f[t-128], z0f[t-128]), __fmul_rn(v0f[t-128], ea));
                }
                tmpf[t] = v;
            }
            __syncthreads();
            if (t < 32) {
                float acc = 0.0f;
                for (int p = 0; p < 512; ++p) acc = fmaf(tmpf[p], W0g[(128+p)*32 + t], acc);
                Hf[t][j] = acc;
            }
            __syncthreads();
        }
    }

    // ---- A = h1 + eps I; rhs = jcob - h2@q ----
    if (t < 256) {
        int i = t >> 4, jj = t & 15;
        Af[i][jj] = (i == jj) ? __fadd_rn(Hf[16+i][jj], 1.0e-3f) : Hf[16+i][jj];
    }
    if (t >= 256 && t < 272) {
        int i = t - 256;
        float dd = 0.0f;
        for (int jj = 0; jj < 16; ++jj) dd = fmaf(Hf[i][jj], uf[jj], dd);
        rf[i] = __fsub_rn(Hf[i][16], dd);
    }
    __syncthreads();

    // sgetf2
    for (int j = 0; j < 16; ++j) {
        if (t == 0) {
            int p = j; float best = fabsf(Af[j][j]);
            for (int r = j+1; r < 16; ++r) {
                float v = fabsf(Af[r][j]);
                if (v > best) { best = v; p = r; }
            }
            ipiv[j] = p; pivS = p;
        }
        __syncthreads();
        int piv = pivS;
        if (piv != j && t < 16) {
            float tv = Af[j][t]; Af[j][t] = Af[piv][t]; Af[piv][t] = tv;
        }
        __syncthreads();
        float recip = 1.0f / Af[j][j];
        if (t > j && t < 16) Af[t][j] = __fmul_rn(Af[t][j], recip);
        __syncthreads();
        if (t < 256) {
            int i = t >> 4, k = t & 15;
            if (i > j && k > j) Af[i][k] = fmaf(-Af[i][j], Af[j][k], Af[i][k]);
        }
        __syncthreads();
    }

    // sgetri: strti2 + descending-j sweep + reverse column pivots
    if (t == 0) {
        for (int j = 0; j < 16; ++j) {
            float ajj_inv = 1.0f / Af[j][j];
            Af[j][j] = ajj_inv;
            float ajj = -ajj_inv;
            for (int j2 = 0; j2 < j; ++j2) {
                float temp = Af[j2][j];
                if (temp != 0.0f)
                    for (int i = 0; i < j2; ++i)
                        Af[i][j] = fmaf(temp, Af[i][j2], Af[i][j]);
                Af[j2][j] = __fmul_rn(Af[j2][j], Af[j2][j2]);
            }
            for (int i = 0; i < j; ++i) Af[i][j] = __fmul_rn(Af[i][j], ajj);
        }
    }
    __syncthreads();
    for (int j = 15; j >= 0; --j) {
        if (t > j && t < 16) { wkc[t] = Af[t][j]; Af[t][j] = 0.0f; }
        __syncthreads();
        if (t < 16) {
            float acc = Af[t][j];
            for (int k = j+1; k < 16; ++k) acc = fmaf(-wkc[k], Af[t][k], acc);
            Af[t][j] = acc;
        }
        __syncthreads();
    }
    if (t < 16) {
        for (int j = 15; j >= 0; --j) {
            int jp = ipiv[j];
            if (jp != j) { float tv = Af[t][j]; Af[t][j] = Af[t][jp]; Af[t][jp] = tv; }
        }
    }
    __syncthreads();

    // qdd = inv @ rhs
    if (t < 16) {
        float acc = 0.0f;
        for (int jj = 0; jj < 16; ++jj) acc = fmaf(Af[t][jj], rf[jj], acc);
        qdo[t] = acc;
    }
    __syncthreads();

    // ---- outputs (gate is true on this path) ----
    if (t < 16)  out[s*16 + t] = qdo[t];
    if (t == 16) out[(size_t)B*16 + s] = y1 / y2;
    if (t == 17) out[(size_t)B*17 + s] = y2;
}

extern "C" void kernel_launch(void* const* d_in, const int* in_sizes, int n_in,
                              void* d_out, int out_size, void* d_ws, size_t ws_size,
                              hipStream_t stream) {
    (void)n_in; (void)out_size;
    const float* x  = (const float*)d_in[0];
    const float* W0 = (const float*)d_in[1];
    const float* b0 = (const float*)d_in[2];
    const float* W1 = (const float*)d_in[3];
    const float* b1 = (const float*)d_in[4];
    const float* Wo = (const float*)d_in[5];
    const float* bo = (const float*)d_in[6];
    const int B = in_sizes[0] / 32;
    const size_t need = (size_t)384 * 512 * sizeof(float);
    float* w1t = (d_ws != nullptr && ws_size >= need) ? (float*)d_ws : nullptr;
    if (w1t) {
        hipLaunchKernelGGL(transpose_w1, dim3((384*512 + 255)/256), dim3(256), 0, stream,
                           W1, w1t);
    }
    hipLaunchKernelGGL(leql_f32_kernel, dim3(B), dim3(512), 0, stream,
                       x, W0, b0, W1, b1, Wo, bo, w1t, (float*)d_out, B);
}

// Round 8
// 836.870 us; speedup vs baseline: 3.9264x; 2.3082x over previous
//
#include <hip/hip_runtime.h>
#include <cmath>

// Full transpose of the used W1 rows: w1tF[m][n'] = W1[128+n'][m],
// m=0..511 (input dim), n'=0..511 (output row - 128). 1 MB.
// Lets the row-pattern GEMVs (z1, zd1) read coalesced across lanes.
__global__ void transpose_w1(const float* __restrict__ W1g, float* __restrict__ w1t) {
    int idx = blockIdx.x * 256 + threadIdx.x;
    if (idx < 512*512) {
        int m = idx >> 9;          // 0..511
        int p = idx & 511;         // n' = 0..511
        w1t[idx] = W1g[(size_t)(128+p)*512 + m];
    }
}

// One workgroup (512 threads) per sample. Based on the R7 passing kernel
// (absmax 4096). Memory-pattern changes only (bit-identical arithmetic):
//  * z1 / zd1 GEMVs read w1tF coalesced (at fixed m, lanes read consecutive
//    addresses), ascending m, same fmaf association.
//  * v0 / vd0 GEMVs reverted to the ORIGINAL W1g column access (which was
//    already coalesced; R7's w1t read there was a pessimization).
__global__ __launch_bounds__(512, 6)
void leql_f32_kernel(const float* __restrict__ x,
                     const float* __restrict__ W0g, const float* __restrict__ b0g,
                     const float* __restrict__ W1g, const float* __restrict__ b1g,
                     const float* __restrict__ Wog, const float* __restrict__ bog,
                     const float* __restrict__ w1t,
                     float* __restrict__ out, int B)
{
    __shared__ float uf[32];
    __shared__ float WoS[1024];
    __shared__ float z0f[512], z1f[512];
    __shared__ float s0f[256], c0f[256], s1f[256], c1f[256];
    __shared__ float h1df[512];
    __shared__ float whatf[384];
    __shared__ float v0f[384];
    __shared__ float tmpf[512];          // also holds h0, then h1 (aliased)
    __shared__ __align__(16) float hd0a[4][384];
    __shared__ float zd1a[4][512];
    __shared__ float vd0f[384];
    __shared__ float Hf[32][17];
    __shared__ float yvf[2], ydf[2];
    __shared__ float Af[16][33], rf[16], qdo[16];
    __shared__ float wkc[16];
    __shared__ int ipiv[16];
    __shared__ int pivS;

    const int t = threadIdx.x;
    const int s = blockIdx.x;

    if (t < 32) uf[t] = x[s*32 + t];
    WoS[t] = Wog[t]; WoS[512+t] = Wog[512+t];
    __syncthreads();

    // ---- forward ----
    {
        const float* wr = &W0g[(128+t)*32];
        float acc = 0.0f;
        for (int c = 0; c < 32; ++c) acc = fmaf(wr[c], uf[c], acc);
        z0f[t] = __fadd_rn(acc, b0g[128+t]);
    }
    __syncthreads();
    if (t < 256) { s0f[t] = sinf(z0f[t]); c0f[t] = cosf(z0f[t]); }
    __syncthreads();
    if (t < 128)      tmpf[t] = 1.0f;                          // h0
    else if (t < 256) tmpf[t] = s0f[t-128];
    else if (t < 384) tmpf[t] = c0f[t-128];
    else              tmpf[t] = __fmul_rn(z0f[t-128], z0f[t]);
    __syncthreads();
    {
        float acc = 0.0f;
        if (w1t) {
            // coalesced: at fixed m, lanes t read consecutive w1t[m*512+t]
            const float* wt = &w1t[t];
            for (int m = 0; m < 512; ++m)
                acc = fmaf(wt[(size_t)m*512], tmpf[m], acc);
        } else {
            const float* wr = &W1g[(size_t)(128+t)*512];
            for (int m = 0; m < 512; m += 4) {
                const float4 w = *(const float4*)(wr + m);
                acc = fmaf(w.x, tmpf[m+0], acc);
                acc = fmaf(w.y, tmpf[m+1], acc);
                acc = fmaf(w.z, tmpf[m+2], acc);
                acc = fmaf(w.w, tmpf[m+3], acc);
            }
        }
        z1f[t] = __fadd_rn(acc, b1g[128+t]);
    }
    __syncthreads();
    if (t < 256) { s1f[t] = sinf(z1f[t]); c1f[t] = cosf(z1f[t]); }
    __syncthreads();
    if (t < 128)      tmpf[t] = 1.0f;                          // h1
    else if (t < 256) tmpf[t] = s1f[t-128];
    else if (t < 384) tmpf[t] = c1f[t-128];
    else              tmpf[t] = __fmul_rn(z1f[t-128], z1f[t]);
    __syncthreads();
    if (t < 2) {
        float acc = 0.0f;
        for (int n = 0; n < 512; ++n) acc = fmaf(WoS[t*512 + n], tmpf[n], acc);
        yvf[t] = __fadd_rn(acc, bog[t]);
    }
    __syncthreads();

    // ---- quotient-rule seeds, jax-lax form ----
    const float y1 = yvf[0], y2 = yvf[1];

    // theta-gate early exit (bit-exact: reference where() zeroes jcob/h1/h2)
    if (!(y2 > 0.5f)) {
        if (t < 16)  out[s*16 + t] = 0.0f;
        if (t == 16) out[(size_t)B*16 + s] = 0.0f;
        if (t == 17) out[(size_t)B*17 + s] = y2;
        return;
    }

    const float y2sq = __fmul_rn(y2, y2);
    const float r2 = 1.0f / y2sq;                       // integer_pow(y2,-2)
    const float r3 = 1.0f / __fmul_rn(y2sq, y2);        // integer_pow(y2,-3)
    const float sd1f = 1.0f / y2;                       // div VJP wrt numerator
    const float sd2f = __fmul_rn(-y1, r2);              // mul(mul(neg(ct),y1),y2^-2)

    // ---- base reverse pass ----
    if (t < 384) {                                       // Wo^T @ seed: fmaf k-chain
        float acc = fmaf(WoS[128+t], sd1f, 0.0f);
        whatf[t] = fmaf(WoS[512+128+t], sd2f, acc);
    }
    __syncthreads();
    {
        float v;
        if (t < 128)      v =  __fmul_rn(whatf[t],     c1f[t]);
        else if (t < 256) v = -__fmul_rn(whatf[t],     s1f[t]);
        else if (t < 384) v =  __fmul_rn(whatf[t],     z1f[t+128]);
        else              v =  __fmul_rn(whatf[t-128], z1f[t-128]);
        tmpf[t] = v;
    }
    __syncthreads();
    if (t < 384) {
        // original column access: at fixed p, lanes read consecutive (coalesced)
        const float* wc = &W1g[(size_t)128*512 + 128 + t];
        float acc = 0.0f;
        for (int p = 0; p < 512; ++p) acc = fmaf(tmpf[p], wc[(size_t)p*512], acc);
        v0f[t] = acc;
    }
    __syncthreads();
    {
        float v;
        if (t < 128)      v =  __fmul_rn(v0f[t],     c0f[t]);
        else if (t < 256) v = -__fmul_rn(v0f[t],     s0f[t]);
        else if (t < 384) v =  __fmul_rn(v0f[t],     z0f[t+128]);
        else              v =  __fmul_rn(v0f[t-128], z0f[t-128]);
        tmpf[t] = v;
    }
    __syncthreads();
    if (t < 32) {
        float acc = 0.0f;
        for (int p = 0; p < 512; ++p) acc = fmaf(tmpf[p], W0g[(128+p)*32 + t], acc);
        Hf[t][16] = acc;
    }
    __syncthreads();

    // ---- 16 tangent passes: 4 groups of 4 batched columns ----
    for (int g = 0; g < 4; ++g) {
        const int cj0 = 16 + g*4;

        // hd0 for 4 columns (per-column scalar formulas verbatim)
        if (t < 384) {
            if (t < 128) {
                const float4 e = *(const float4*)&W0g[(128+t)*32 + cj0];
                const float cth = c0f[t];
                hd0a[0][t] = __fmul_rn(cth, e.x);
                hd0a[1][t] = __fmul_rn(cth, e.y);
                hd0a[2][t] = __fmul_rn(cth, e.z);
                hd0a[3][t] = __fmul_rn(cth, e.w);
            } else if (t < 256) {
                const float4 e = *(const float4*)&W0g[(128+t)*32 + cj0];
                const float sth = s0f[t];
                hd0a[0][t] = -__fmul_rn(sth, e.x);
                hd0a[1][t] = -__fmul_rn(sth, e.y);
                hd0a[2][t] = -__fmul_rn(sth, e.z);
                hd0a[3][t] = -__fmul_rn(sth, e.w);
            } else {
                const int i = t - 256;
                const float4 p4 = *(const float4*)&W0g[(384+i)*32 + cj0];
                const float4 q4 = *(const float4*)&W0g[(512+i)*32 + cj0];
                const float za = z0f[384+i], zb = z0f[256+i];
                hd0a[0][t] = __fadd_rn(__fmul_rn(p4.x, za), __fmul_rn(zb, q4.x));
                hd0a[1][t] = __fadd_rn(__fmul_rn(p4.y, za), __fmul_rn(zb, q4.y));
                hd0a[2][t] = __fadd_rn(__fmul_rn(p4.z, za), __fmul_rn(zb, q4.z));
                hd0a[3][t] = __fadd_rn(__fmul_rn(p4.w, za), __fmul_rn(zb, q4.w));
            }
        }
        __syncthreads();

        // zd1 for 4 columns: ONE W1 sweep (coalesced via w1t), 4 ascending chains
        {
            float a0=0.0f, a1=0.0f, a2=0.0f, a3=0.0f;
            if (w1t) {
                // element = W1[(128+t)*512 + 128+m] = w1t[(128+m)*512 + t]
                const float* wt = &w1t[(size_t)128*512 + t];
                for (int m = 0; m < 384; ++m) {
                    const float w = wt[(size_t)m*512];
                    const float h0 = hd0a[0][m];
                    const float h1 = hd0a[1][m];
                    const float h2 = hd0a[2][m];
                    const float h3 = hd0a[3][m];
                    a0 = fmaf(w, h0, a0);
                    a1 = fmaf(w, h1, a1);
                    a2 = fmaf(w, h2, a2);
                    a3 = fmaf(w, h3, a3);
                }
            } else {
                const float* wr = &W1g[(size_t)(128+t)*512 + 128];
                for (int m = 0; m < 384; m += 4) {
                    const float4 w  = *(const float4*)(wr + m);
                    const float4 h0 = *(const float4*)&hd0a[0][m];
                    const float4 h1 = *(const float4*)&hd0a[1][m];
                    const float4 h2 = *(const float4*)&hd0a[2][m];
                    const float4 h3 = *(const float4*)&hd0a[3][m];
                    a0 = fmaf(w.x, h0.x, a0); a0 = fmaf(w.y, h0.y, a0);
                    a0 = fmaf(w.z, h0.z, a0); a0 = fmaf(w.w, h0.w, a0);
                    a1 = fmaf(w.x, h1.x, a1); a1 = fmaf(w.y, h1.y, a1);
                    a1 = fmaf(w.z, h1.z, a1); a1 = fmaf(w.w, h1.w, a1);
                    a2 = fmaf(w.x, h2.x, a2); a2 = fmaf(w.y, h2.y, a2);
                    a2 = fmaf(w.z, h2.z, a2); a2 = fmaf(w.w, h2.w, a2);
                    a3 = fmaf(w.x, h3.x, a3); a3 = fmaf(w.y, h3.y, a3);
                    a3 = fmaf(w.z, h3.z, a3); a3 = fmaf(w.w, h3.w, a3);
                }
            }
            zd1a[0][t]=a0; zd1a[1][t]=a1; zd1a[2][t]=a2; zd1a[3][t]=a3;
        }
        __syncthreads();

        for (int jj = 0; jj < 4; ++jj) {
            const int j = g*4 + jj;
            const int cj = 16 + j;
            const float* zd1f = zd1a[jj];      // per-j view, code below verbatim
            {
                float v;
                if (t < 128)      v = 0.0f;
                else if (t < 256) v =  __fmul_rn(c1f[t-128], zd1f[t-128]);
                else if (t < 384) v = -__fmul_rn(s1f[t-128], zd1f[t-128]);
                else              v = __fadd_rn(__fmul_rn(zd1f[t-128], z1f[t]),
                                                __fmul_rn(z1f[t-128], zd1f[t]));
                h1df[t] = v;
            }
            __syncthreads();
            if (t < 2) {
                float acc = 0.0f;
                for (int n = 0; n < 512; ++n) acc = fmaf(WoS[t*512 + n], h1df[n], acc);
                ydf[t] = acc;
            }
            __syncthreads();
            {   // vdot1, jax-JVP associations
                float yd1 = ydf[0], yd2 = ydf[1];
                float sdot1 = __fmul_rn(-yd2, r2);
                float dr2 = __fmul_rn(__fmul_rn(yd2, -2.0f), r3);
                float sdot2 = __fadd_rn(__fmul_rn(-yd1, r2), __fmul_rn(-y1, dr2));
                int n = (t < 384) ? (128 + t) : t;
                float wd = fmaf(WoS[512+n], sdot2, fmaf(WoS[n], sdot1, 0.0f));
                float v;
                if (t < 128) {                       // sin node: what*cos(z1)
                    float dcs = __fmul_rn(zd1f[t], -s1f[t]);
                    v = __fadd_rn(__fmul_rn(wd, c1f[t]), __fmul_rn(whatf[t], dcs));
                } else if (t < 256) {                // cos node: what*(-sin(z1))
                    float dsn = __fmul_rn(zd1f[t], c1f[t]);
                    v = __fadd_rn(__fmul_rn(wd, -s1f[t]), __fmul_rn(whatf[t], -dsn));
                } else if (t < 384) {
                    v = __fadd_rn(__fmul_rn(wd, z1f[t+128]),
                                  __fmul_rn(whatf[t], zd1f[t+128]));
                } else {
                    v = __fadd_rn(__fmul_rn(wd, z1f[t-128]),
                                  __fmul_rn(whatf[t-128], zd1f[t-128]));
                }
                tmpf[t] = v;
            }
            __syncthreads();
            if (t < 384) {
                // original column access (coalesced across lanes)
                const float* wc = &W1g[(size_t)128*512 + 128 + t];
                float acc = 0.0f;
                for (int p = 0; p < 512; ++p) acc = fmaf(tmpf[p], wc[(size_t)p*512], acc);
                vd0f[t] = acc;
            }
            __syncthreads();
            {   // dzdot0, jax-JVP associations
                float v;
                if (t < 128) {                       // sin z0 node: v0*cos(z0)
                    float e = W0g[(128+t)*32 + cj];
                    float dcs = __fmul_rn(e, -s0f[t]);
                    v = __fadd_rn(__fmul_rn(vd0f[t], c0f[t]), __fmul_rn(v0f[t], dcs));
                } else if (t < 256) {                // cos z0 node: v0*(-sin(z0))
                    float e = W0g[(128+t)*32 + cj];
                    float dsn = __fmul_rn(e, c0f[t]);
                    v = __fadd_rn(__fmul_rn(vd0f[t], -s0f[t]), __fmul_rn(v0f[t], -dsn));
                } else if (t < 384) {
                    float eb = W0g[(256+t)*32 + cj];
                    v = __fadd_rn(__fmul_rn(vd0f[t], z0f[t+128]), __fmul_rn(v0f[t], eb));
                } else {
                    float ea = W0g[t*32 + cj];
                    v = __fadd_rn(__fmul_rn(vd0f[t-128], z0f[t-128]), __fmul_rn(v0f[t-128], ea));
                }
                tmpf[t] = v;
            }
            __syncthreads();
            if (t < 32) {
                float acc = 0.0f;
                for (int p = 0; p < 512; ++p) acc = fmaf(tmpf[p], W0g[(128+p)*32 + t], acc);
                Hf[t][j] = acc;
            }
            __syncthreads();
        }
    }

    // ---- A = h1 + eps I; rhs = jcob - h2@q ----
    if (t < 256) {
        int i = t >> 4, jj = t & 15;
        Af[i][jj] = (i == jj) ? __fadd_rn(Hf[16+i][jj], 1.0e-3f) : Hf[16+i][jj];
    }
    if (t >= 256 && t < 272) {
        int i = t - 256;
        float dd = 0.0f;
        for (int jj = 0; jj < 16; ++jj) dd = fmaf(Hf[i][jj], uf[jj], dd);
        rf[i] = __fsub_rn(Hf[i][16], dd);
    }
    __syncthreads();

    // sgetf2
    for (int j = 0; j < 16; ++j) {
        if (t == 0) {
            int p = j; float best = fabsf(Af[j][j]);
            for (int r = j+1; r < 16; ++r) {
                float v = fabsf(Af[r][j]);
                if (v > best) { best = v; p = r; }
            }
            ipiv[j] = p; pivS = p;
        }
        __syncthreads();
        int piv = pivS;
        if (piv != j && t < 16) {
            float tv = Af[j][t]; Af[j][t] = Af[piv][t]; Af[piv][t] = tv;
        }
        __syncthreads();
        float recip = 1.0f / Af[j][j];
        if (t > j && t < 16) Af[t][j] = __fmul_rn(Af[t][j], recip);
        __syncthreads();
        if (t < 256) {
            int i = t >> 4, k = t & 15;
            if (i > j && k > j) Af[i][k] = fmaf(-Af[i][j], Af[j][k], Af[i][k]);
        }
        __syncthreads();
    }

    // sgetri: strti2 + descending-j sweep + reverse column pivots
    if (t == 0) {
        for (int j = 0; j < 16; ++j) {
            float ajj_inv = 1.0f / Af[j][j];
            Af[j][j] = ajj_inv;
            float ajj = -ajj_inv;
            for (int j2 = 0; j2 < j; ++j2) {
                float temp = Af[j2][j];
                if (temp != 0.0f)
                    for (int i = 0; i < j2; ++i)
                        Af[i][j] = fmaf(temp, Af[i][j2], Af[i][j]);
                Af[j2][j] = __fmul_rn(Af[j2][j], Af[j2][j2]);
            }
            for (int i = 0; i < j; ++i) Af[i][j] = __fmul_rn(Af[i][j], ajj);
        }
    }
    __syncthreads();
    for (int j = 15; j >= 0; --j) {
        if (t > j && t < 16) { wkc[t] = Af[t][j]; Af[t][j] = 0.0f; }
        __syncthreads();
        if (t < 16) {
            float acc = Af[t][j];
            for (int k = j+1; k < 16; ++k) acc = fmaf(-wkc[k], Af[t][k], acc);
            Af[t][j] = acc;
        }
        __syncthreads();
    }
    if (t < 16) {
        for (int j = 15; j >= 0; --j) {
            int jp = ipiv[j];
            if (jp != j) { float tv = Af[t][j]; Af[t][j] = Af[t][jp]; Af[t][jp] = tv; }
        }
    }
    __syncthreads();

    // qdd = inv @ rhs
    if (t < 16) {
        float acc = 0.0f;
        for (int jj = 0; jj < 16; ++jj) acc = fmaf(Af[t][jj], rf[jj], acc);
        qdo[t] = acc;
    }
    __syncthreads();

    // ---- outputs (gate is true on this path) ----
    if (t < 16)  out[s*16 + t] = qdo[t];
    if (t == 16) out[(size_t)B*16 + s] = y1 / y2;
    if (t == 17) out[(size_t)B*17 + s] = y2;
}

extern "C" void kernel_launch(void* const* d_in, const int* in_sizes, int n_in,
                              void* d_out, int out_size, void* d_ws, size_t ws_size,
                              hipStream_t stream) {
    (void)n_in; (void)out_size;
    const float* x  = (const float*)d_in[0];
    const float* W0 = (const float*)d_in[1];
    const float* b0 = (const float*)d_in[2];
    const float* W1 = (const float*)d_in[3];
    const float* b1 = (const float*)d_in[4];
    const float* Wo = (const float*)d_in[5];
    const float* bo = (const float*)d_in[6];
    const int B = in_sizes[0] / 32;
    const size_t need = (size_t)512 * 512 * sizeof(float);
    float* w1t = (d_ws != nullptr && ws_size >= need) ? (float*)d_ws : nullptr;
    if (w1t) {
        hipLaunchKernelGGL(transpose_w1, dim3((512*512 + 255)/256), dim3(256), 0, stream,
                           W1, w1t);
    }
    hipLaunchKernelGGL(leql_f32_kernel, dim3(B), dim3(512), 0, stream,
                       x, W0, b0, W1, b1, Wo, bo, w1t, (float*)d_out, B);
}

// Round 11
// 782.224 us; speedup vs baseline: 4.2007x; 1.0699x over previous
//
#include <hip/hip_runtime.h>
#include <cmath>

// Full transpose of the used W1 rows: w1tF[m][n'] = W1[128+n'][m].
__global__ void transpose_w1(const float* __restrict__ W1g, float* __restrict__ w1t) {
    int idx = blockIdx.x * 256 + threadIdx.x;
    if (idx < 512*512) {
        int m = idx >> 9;
        int p = idx & 511;
        w1t[idx] = W1g[(size_t)(128+p)*512 + m];
    }
}

// One workgroup (512 threads) per sample. VERBATIM the R8 passing kernel
// (absmax 4096, 837us) with ONE change: vd0 is batched across the 4 columns
// of each group. vdot1 writes tmpa[jj] (storage rename of R8's tmpf); ONE
// coalesced W1-column sweep computes 4 ascending chains (shared load is
// bit-exact); dzdot0/Hf run verbatim per jj reading vd0a[jj]/tmpa[jj].
// h1d, ydf (full 0..511 loop over h1df), vdot1, dzdot0, Hf chains unchanged.
__global__ __launch_bounds__(512, 6)
void leql_f32_kernel(const float* __restrict__ x,
                     const float* __restrict__ W0g, const float* __restrict__ b0g,
                     const float* __restrict__ W1g, const float* __restrict__ b1g,
                     const float* __restrict__ Wog, const float* __restrict__ bog,
                     const float* __restrict__ w1t,
                     float* __restrict__ out, int B)
{
    __shared__ float uf[32];
    __shared__ float WoS[1024];
    __shared__ float z0f[512], z1f[512];
    __shared__ float s0f[256], c0f[256], s1f[256], c1f[256];
    __shared__ float h1df[512];
    __shared__ float whatf[384];
    __shared__ float v0f[384];
    __shared__ __align__(16) float hd0a[4][384];
    __shared__ float zd1a[4][512];
    __shared__ float tmpa[4][512];       // tmpa[0] doubles as h0/h1/base scratch
    __shared__ float vd0a[4][384];
    __shared__ float Hf[32][17];
    __shared__ float yvf[2], ydf[2];
    __shared__ float Af[16][33], rf[16], qdo[16], wkc[16];
    __shared__ int ipiv[16];
    __shared__ int pivS;

    const int t = threadIdx.x;
    const int s = blockIdx.x;

    if (t < 32) uf[t] = x[s*32 + t];
    WoS[t] = Wog[t]; WoS[512+t] = Wog[512+t];
    __syncthreads();

    // ---- forward ----
    {
        const float* wr = &W0g[(128+t)*32];
        float acc = 0.0f;
        for (int c = 0; c < 32; ++c) acc = fmaf(wr[c], uf[c], acc);
        z0f[t] = __fadd_rn(acc, b0g[128+t]);
    }
    __syncthreads();
    if (t < 256) { s0f[t] = sinf(z0f[t]); c0f[t] = cosf(z0f[t]); }
    __syncthreads();
    if (t < 128)      tmpa[0][t] = 1.0f;                          // h0
    else if (t < 256) tmpa[0][t] = s0f[t-128];
    else if (t < 384) tmpa[0][t] = c0f[t-128];
    else              tmpa[0][t] = __fmul_rn(z0f[t-128], z0f[t]);
    __syncthreads();
    {
        float acc = 0.0f;
        if (w1t) {
            const float* wt = &w1t[t];
            for (int m = 0; m < 512; ++m)
                acc = fmaf(wt[(size_t)m*512], tmpa[0][m], acc);
        } else {
            const float* wr = &W1g[(size_t)(128+t)*512];
            for (int m = 0; m < 512; m += 4) {
                const float4 w = *(const float4*)(wr + m);
                acc = fmaf(w.x, tmpa[0][m+0], acc);
                acc = fmaf(w.y, tmpa[0][m+1], acc);
                acc = fmaf(w.z, tmpa[0][m+2], acc);
                acc = fmaf(w.w, tmpa[0][m+3], acc);
            }
        }
        z1f[t] = __fadd_rn(acc, b1g[128+t]);
    }
    __syncthreads();
    if (t < 256) { s1f[t] = sinf(z1f[t]); c1f[t] = cosf(z1f[t]); }
    __syncthreads();
    if (t < 128)      tmpa[0][t] = 1.0f;                          // h1
    else if (t < 256) tmpa[0][t] = s1f[t-128];
    else if (t < 384) tmpa[0][t] = c1f[t-128];
    else              tmpa[0][t] = __fmul_rn(z1f[t-128], z1f[t]);
    __syncthreads();
    if (t < 2) {
        float acc = 0.0f;
        for (int n = 0; n < 512; ++n) acc = fmaf(WoS[t*512 + n], tmpa[0][n], acc);
        yvf[t] = __fadd_rn(acc, bog[t]);
    }
    __syncthreads();

    const float y1 = yvf[0], y2 = yvf[1];

    // theta-gate early exit (bit-exact: reference where() zeroes jcob/h1/h2)
    if (!(y2 > 0.5f)) {
        if (t < 16)  out[s*16 + t] = 0.0f;
        if (t == 16) out[(size_t)B*16 + s] = 0.0f;
        if (t == 17) out[(size_t)B*17 + s] = y2;
        return;
    }

    const float y2sq = __fmul_rn(y2, y2);
    const float r2 = 1.0f / y2sq;                       // integer_pow(y2,-2)
    const float r3 = 1.0f / __fmul_rn(y2sq, y2);        // integer_pow(y2,-3)
    const float sd1f = 1.0f / y2;                       // div VJP wrt numerator
    const float sd2f = __fmul_rn(-y1, r2);              // mul(mul(neg(ct),y1),y2^-2)

    // ---- base reverse pass ----
    if (t < 384) {
        float acc = fmaf(WoS[128+t], sd1f, 0.0f);
        whatf[t] = fmaf(WoS[512+128+t], sd2f, acc);
    }
    __syncthreads();
    {
        float v;
        if (t < 128)      v =  __fmul_rn(whatf[t],     c1f[t]);
        else if (t < 256) v = -__fmul_rn(whatf[t],     s1f[t]);
        else if (t < 384) v =  __fmul_rn(whatf[t],     z1f[t+128]);
        else              v =  __fmul_rn(whatf[t-128], z1f[t-128]);
        tmpa[0][t] = v;
    }
    __syncthreads();
    if (t < 384) {
        const float* wc = &W1g[(size_t)128*512 + 128 + t];
        float acc = 0.0f;
        for (int p = 0; p < 512; ++p) acc = fmaf(tmpa[0][p], wc[(size_t)p*512], acc);
        v0f[t] = acc;
    }
    __syncthreads();
    {
        float v;
        if (t < 128)      v =  __fmul_rn(v0f[t],     c0f[t]);
        else if (t < 256) v = -__fmul_rn(v0f[t],     s0f[t]);
        else if (t < 384) v =  __fmul_rn(v0f[t],     z0f[t+128]);
        else              v =  __fmul_rn(v0f[t-128], z0f[t-128]);
        tmpa[0][t] = v;
    }
    __syncthreads();
    if (t < 32) {
        float acc = 0.0f;
        for (int p = 0; p < 512; ++p) acc = fmaf(tmpa[0][p], W0g[(128+p)*32 + t], acc);
        Hf[t][16] = acc;
    }
    __syncthreads();

    // ---- 16 tangent passes: 4 groups of 4 ----
    for (int g = 0; g < 4; ++g) {
        const int cj0 = 16 + g*4;

        // hd0 for 4 columns (verbatim R8)
        if (t < 384) {
            if (t < 128) {
                const float4 e = *(const float4*)&W0g[(128+t)*32 + cj0];
                const float cth = c0f[t];
                hd0a[0][t] = __fmul_rn(cth, e.x);
                hd0a[1][t] = __fmul_rn(cth, e.y);
                hd0a[2][t] = __fmul_rn(cth, e.z);
                hd0a[3][t] = __fmul_rn(cth, e.w);
            } else if (t < 256) {
                const float4 e = *(const float4*)&W0g[(128+t)*32 + cj0];
                const float sth = s0f[t];
                hd0a[0][t] = -__fmul_rn(sth, e.x);
                hd0a[1][t] = -__fmul_rn(sth, e.y);
                hd0a[2][t] = -__fmul_rn(sth, e.z);
                hd0a[3][t] = -__fmul_rn(sth, e.w);
            } else {
                const int i = t - 256;
                const float4 p4 = *(const float4*)&W0g[(384+i)*32 + cj0];
                const float4 q4 = *(const float4*)&W0g[(512+i)*32 + cj0];
                const float za = z0f[384+i], zb = z0f[256+i];
                hd0a[0][t] = __fadd_rn(__fmul_rn(p4.x, za), __fmul_rn(zb, q4.x));
                hd0a[1][t] = __fadd_rn(__fmul_rn(p4.y, za), __fmul_rn(zb, q4.y));
                hd0a[2][t] = __fadd_rn(__fmul_rn(p4.z, za), __fmul_rn(zb, q4.z));
                hd0a[3][t] = __fadd_rn(__fmul_rn(p4.w, za), __fmul_rn(zb, q4.w));
            }
        }
        __syncthreads();

        // zd1 for 4 columns (verbatim R8: one coalesced w1t sweep, 4 chains)
        {
            float a0=0.0f, a1=0.0f, a2=0.0f, a3=0.0f;
            if (w1t) {
                const float* wt = &w1t[(size_t)128*512 + t];
                for (int m = 0; m < 384; ++m) {
                    const float w = wt[(size_t)m*512];
                    a0 = fmaf(w, hd0a[0][m], a0);
                    a1 = fmaf(w, hd0a[1][m], a1);
                    a2 = fmaf(w, hd0a[2][m], a2);
                    a3 = fmaf(w, hd0a[3][m], a3);
                }
            } else {
                const float* wr = &W1g[(size_t)(128+t)*512 + 128];
                for (int m = 0; m < 384; m += 4) {
                    const float4 w  = *(const float4*)(wr + m);
                    const float4 h0 = *(const float4*)&hd0a[0][m];
                    const float4 h1 = *(const float4*)&hd0a[1][m];
                    const float4 h2 = *(const float4*)&hd0a[2][m];
                    const float4 h3 = *(const float4*)&hd0a[3][m];
                    a0 = fmaf(w.x, h0.x, a0); a0 = fmaf(w.y, h0.y, a0);
                    a0 = fmaf(w.z, h0.z, a0); a0 = fmaf(w.w, h0.w, a0);
                    a1 = fmaf(w.x, h1.x, a1); a1 = fmaf(w.y, h1.y, a1);
                    a1 = fmaf(w.z, h1.z, a1); a1 = fmaf(w.w, h1.w, a1);
                    a2 = fmaf(w.x, h2.x, a2); a2 = fmaf(w.y, h2.y, a2);
                    a2 = fmaf(w.z, h2.z, a2); a2 = fmaf(w.w, h2.w, a2);
                    a3 = fmaf(w.x, h3.x, a3); a3 = fmaf(w.y, h3.y, a3);
                    a3 = fmaf(w.z, h3.z, a3); a3 = fmaf(w.w, h3.w, a3);
                }
            }
            zd1a[0][t]=a0; zd1a[1][t]=a1; zd1a[2][t]=a2; zd1a[3][t]=a3;
        }
        __syncthreads();

        // first sub-loop: h1d, ydf, vdot1 -- VERBATIM R8, vdot1 -> tmpa[jj]
        for (int jj = 0; jj < 4; ++jj) {
            const float* zd1f = zd1a[jj];
            {
                float v;
                if (t < 128)      v = 0.0f;
                else if (t < 256) v =  __fmul_rn(c1f[t-128], zd1f[t-128]);
                else if (t < 384) v = -__fmul_rn(s1f[t-128], zd1f[t-128]);
                else              v = __fadd_rn(__fmul_rn(zd1f[t-128], z1f[t]),
                                                __fmul_rn(z1f[t-128], zd1f[t]));
                h1df[t] = v;
            }
            __syncthreads();
            if (t < 2) {
                float acc = 0.0f;
                for (int n = 0; n < 512; ++n) acc = fmaf(WoS[t*512 + n], h1df[n], acc);
                ydf[t] = acc;
            }
            __syncthreads();
            {   // vdot1, jax-JVP associations (verbatim R8)
                float yd1 = ydf[0], yd2 = ydf[1];
                float sdot1 = __fmul_rn(-yd2, r2);
                float dr2 = __fmul_rn(__fmul_rn(yd2, -2.0f), r3);
                float sdot2 = __fadd_rn(__fmul_rn(-yd1, r2), __fmul_rn(-y1, dr2));
                int n = (t < 384) ? (128 + t) : t;
                float wd = fmaf(WoS[512+n], sdot2, fmaf(WoS[n], sdot1, 0.0f));
                float v;
                if (t < 128) {
                    float dcs = __fmul_rn(zd1f[t], -s1f[t]);
                    v = __fadd_rn(__fmul_rn(wd, c1f[t]), __fmul_rn(whatf[t], dcs));
                } else if (t < 256) {
                    float dsn = __fmul_rn(zd1f[t], c1f[t]);
                    v = __fadd_rn(__fmul_rn(wd, -s1f[t]), __fmul_rn(whatf[t], -dsn));
                } else if (t < 384) {
                    v = __fadd_rn(__fmul_rn(wd, z1f[t+128]),
                                  __fmul_rn(whatf[t], zd1f[t+128]));
                } else {
                    v = __fadd_rn(__fmul_rn(wd, z1f[t-128]),
                                  __fmul_rn(whatf[t-128], zd1f[t-128]));
                }
                tmpa[jj][t] = v;
            }
            __syncthreads();
        }

        // vd0: ONE coalesced W1-column sweep feeds 4 ascending chains
        // (shared load of w is bit-exact; per-chain association = R8)
        if (t < 384) {
            const float* wc = &W1g[(size_t)128*512 + 128 + t];
            float a0=0.0f, a1=0.0f, a2=0.0f, a3=0.0f;
            for (int p = 0; p < 512; ++p) {
                const float w = wc[(size_t)p*512];
                a0 = fmaf(tmpa[0][p], w, a0);
                a1 = fmaf(tmpa[1][p], w, a1);
                a2 = fmaf(tmpa[2][p], w, a2);
                a3 = fmaf(tmpa[3][p], w, a3);
            }
            vd0a[0][t]=a0; vd0a[1][t]=a1; vd0a[2][t]=a2; vd0a[3][t]=a3;
        }
        __syncthreads();

        // second sub-loop: dzdot0 + Hf -- VERBATIM R8 per jj
        for (int jj = 0; jj < 4; ++jj) {
            const int j = g*4 + jj;
            const int cj = 16 + j;
            const float* vd0f = vd0a[jj];
            {
                float v;
                if (t < 128) {
                    float e = W0g[(128+t)*32 + cj];
                    float dcs = __fmul_rn(e, -s0f[t]);
                    v = __fadd_rn(__fmul_rn(vd0f[t], c0f[t]), __fmul_rn(v0f[t], dcs));
                } else if (t < 256) {
                    float e = W0g[(128+t)*32 + cj];
                    float dsn = __fmul_rn(e, c0f[t]);
                    v = __fadd_rn(__fmul_rn(vd0f[t], -s0f[t]), __fmul_rn(v0f[t], -dsn));
                } else if (t < 384) {
                    float eb = W0g[(256+t)*32 + cj];
                    v = __fadd_rn(__fmul_rn(vd0f[t], z0f[t+128]), __fmul_rn(v0f[t], eb));
                } else {
                    float ea = W0g[t*32 + cj];
                    v = __fadd_rn(__fmul_rn(vd0f[t-128], z0f[t-128]), __fmul_rn(v0f[t-128], ea));
                }
                tmpa[jj][t] = v;
            }
            __syncthreads();
            if (t < 32) {
                float acc = 0.0f;
                for (int p = 0; p < 512; ++p)
                    acc = fmaf(tmpa[jj][p], W0g[(128+p)*32 + t], acc);
                Hf[t][j] = acc;
            }
            __syncthreads();
        }
    }

    // ---- A = h1 + eps I; rhs = jcob - h2@q ----
    if (t < 256) {
        int i = t >> 4, jj = t & 15;
        Af[i][jj] = (i == jj) ? __fadd_rn(Hf[16+i][jj], 1.0e-3f) : Hf[16+i][jj];
    }
    if (t >= 256 && t < 272) {
        int i = t - 256;
        float dd = 0.0f;
        for (int jj = 0; jj < 16; ++jj) dd = fmaf(Hf[i][jj], uf[jj], dd);
        rf[i] = __fsub_rn(Hf[i][16], dd);
    }
    __syncthreads();

    // sgetf2
    for (int j = 0; j < 16; ++j) {
        if (t == 0) {
            int p = j; float best = fabsf(Af[j][j]);
            for (int r = j+1; r < 16; ++r) {
                float v = fabsf(Af[r][j]);
                if (v > best) { best = v; p = r; }
            }
            ipiv[j] = p; pivS = p;
        }
        __syncthreads();
        int piv = pivS;
        if (piv != j && t < 16) {
            float tv = Af[j][t]; Af[j][t] = Af[piv][t]; Af[piv][t] = tv;
        }
        __syncthreads();
        float recip = 1.0f / Af[j][j];
        if (t > j && t < 16) Af[t][j] = __fmul_rn(Af[t][j], recip);
        __syncthreads();
        if (t < 256) {
            int i = t >> 4, k = t & 15;
            if (i > j && k > j) Af[i][k] = fmaf(-Af[i][j], Af[j][k], Af[i][k]);
        }
        __syncthreads();
    }

    // sgetri: strti2 + descending-j sweep + reverse column pivots
    if (t == 0) {
        for (int j = 0; j < 16; ++j) {
            float ajj_inv = 1.0f / Af[j][j];
            Af[j][j] = ajj_inv;
            float ajj = -ajj_inv;
            for (int j2 = 0; j2 < j; ++j2) {
                float temp = Af[j2][j];
                if (temp != 0.0f)
                    for (int i = 0; i < j2; ++i)
                        Af[i][j] = fmaf(temp, Af[i][j2], Af[i][j]);
                Af[j2][j] = __fmul_rn(Af[j2][j], Af[j2][j2]);
            }
            for (int i = 0; i < j; ++i) Af[i][j] = __fmul_rn(Af[i][j], ajj);
        }
    }
    __syncthreads();
    for (int j = 15; j >= 0; --j) {
        if (t > j && t < 16) { wkc[t] = Af[t][j]; Af[t][j] = 0.0f; }
        __syncthreads();
        if (t < 16) {
            float acc = Af[t][j];
            for (int k = j+1; k < 16; ++k) acc = fmaf(-wkc[k], Af[t][k], acc);
            Af[t][j] = acc;
        }
        __syncthreads();
    }
    if (t < 16) {
        for (int j = 15; j >= 0; --j) {
            int jp = ipiv[j];
            if (jp != j) { float tv = Af[t][j]; Af[t][j] = Af[t][jp]; Af[t][jp] = tv; }
        }
    }
    __syncthreads();

    // qdd = inv @ rhs
    if (t < 16) {
        float acc = 0.0f;
        for (int jj = 0; jj < 16; ++jj) acc = fmaf(Af[t][jj], rf[jj], acc);
        qdo[t] = acc;
    }
    __syncthreads();

    // ---- outputs (gate is true on this path) ----
    if (t < 16)  out[s*16 + t] = qdo[t];
    if (t == 16) out[(size_t)B*16 + s] = y1 / y2;
    if (t == 17) out[(size_t)B*17 + s] = y2;
}

extern "C" void kernel_launch(void* const* d_in, const int* in_sizes, int n_in,
                              void* d_out, int out_size, void* d_ws, size_t ws_size,
                              hipStream_t stream) {
    (void)n_in; (void)out_size;
    const float* x  = (const float*)d_in[0];
    const float* W0 = (const float*)d_in[1];
    const float* b0 = (const float*)d_in[2];
    const float* W1 = (const float*)d_in[3];
    const float* b1 = (const float*)d_in[4];
    const float* Wo = (const float*)d_in[5];
    const float* bo = (const float*)d_in[6];
    const int B = in_sizes[0] / 32;
    const size_t need = (size_t)512 * 512 * sizeof(float);
    float* w1t = (d_ws != nullptr && ws_size >= need) ? (float*)d_ws : nullptr;
    if (w1t) {
        hipLaunchKernelGGL(transpose_w1, dim3((512*512 + 255)/256), dim3(256), 0, stream,
                           W1, w1t);
    }
    hipLaunchKernelGGL(leql_f32_kernel, dim3(B), dim3(512), 0, stream,
                       x, W0, b0, W1, b1, Wo, bo, w1t, (float*)d_out, B);
}

// Round 13
// 777.441 us; speedup vs baseline: 4.2266x; 1.0062x over previous
//
#include <hip/hip_runtime.h>
#include <cmath>

// Full transpose of the used W1 rows: w1tF[m][n'] = W1[128+n'][m].
__global__ void transpose_w1(const float* __restrict__ W1g, float* __restrict__ w1t) {
    int idx = blockIdx.x * 256 + threadIdx.x;
    if (idx < 512*512) {
        int m = idx >> 9;
        int p = idx & 511;
        w1t[idx] = W1g[(size_t)(128+p)*512 + m];
    }
}

// One workgroup (512 threads) per sample. VERBATIM the R11 passing kernel
// (absmax 4096, 782us) with ONE storage-only change: hd0a / h1df / vd0a /
// solve-arrays have disjoint lifetimes (hd0a dies at the zd1 barrier; h1df
// lives only in the first sub-loop; vd0a born after vdot1, dies at dzdot0;
// solve runs post-tangent) and now share ONE 6144B pool.
// LDS 51200 -> 40448 B  =>  4 blocks/CU (was 3). No arithmetic change.
__global__ __launch_bounds__(512, 6)
void leql_f32_kernel(const float* __restrict__ x,
                     const float* __restrict__ W0g, const float* __restrict__ b0g,
                     const float* __restrict__ W1g, const float* __restrict__ b1g,
                     const float* __restrict__ Wog, const float* __restrict__ bog,
                     const float* __restrict__ w1t,
                     float* __restrict__ out, int B)
{
    __shared__ float uf[32];
    __shared__ float WoS[1024];
    __shared__ float z0f[512], z1f[512];
    __shared__ float s0f[256], c0f[256], s1f[256], c1f[256];
    __shared__ float whatf[384];
    __shared__ float v0f[384];
    __shared__ float zd1a[4][512];
    __shared__ float tmpa[4][512];       // tmpa[0] doubles as h0/h1/base scratch
    __shared__ float Hf[32][17];
    __shared__ float yvf[2], ydf[2];
    __shared__ __align__(16) float pool[1536];   // hd0a -> h1df -> vd0a -> solve
    __shared__ int pivS;

    float (*hd0a)[384] = reinterpret_cast<float(*)[384]>(pool);
    float* h1df        = pool;                                   // [512]
    float (*vd0a)[384] = reinterpret_cast<float(*)[384]>(pool);
    float (*Af)[33]    = reinterpret_cast<float(*)[33]>(pool);   // 528 floats
    float* rf   = pool + 528;   // [16]
    float* qdo  = pool + 544;   // [16]
    float* wkc  = pool + 560;   // [16]
    int*   ipiv = reinterpret_cast<int*>(pool + 576);  // [16]

    const int t = threadIdx.x;
    const int s = blockIdx.x;

    if (t < 32) uf[t] = x[s*32 + t];
    WoS[t] = Wog[t]; WoS[512+t] = Wog[512+t];
    __syncthreads();

    // ---- forward ----
    {
        const float* wr = &W0g[(128+t)*32];
        float acc = 0.0f;
        for (int c = 0; c < 32; ++c) acc = fmaf(wr[c], uf[c], acc);
        z0f[t] = __fadd_rn(acc, b0g[128+t]);
    }
    __syncthreads();
    if (t < 256) { s0f[t] = sinf(z0f[t]); c0f[t] = cosf(z0f[t]); }
    __syncthreads();
    if (t < 128)      tmpa[0][t] = 1.0f;                          // h0
    else if (t < 256) tmpa[0][t] = s0f[t-128];
    else if (t < 384) tmpa[0][t] = c0f[t-128];
    else              tmpa[0][t] = __fmul_rn(z0f[t-128], z0f[t]);
    __syncthreads();
    {
        float acc = 0.0f;
        if (w1t) {
            const float* wt = &w1t[t];
            for (int m = 0; m < 512; ++m)
                acc = fmaf(wt[(size_t)m*512], tmpa[0][m], acc);
        } else {
            const float* wr = &W1g[(size_t)(128+t)*512];
            for (int m = 0; m < 512; m += 4) {
                const float4 w = *(const float4*)(wr + m);
                acc = fmaf(w.x, tmpa[0][m+0], acc);
                acc = fmaf(w.y, tmpa[0][m+1], acc);
                acc = fmaf(w.z, tmpa[0][m+2], acc);
                acc = fmaf(w.w, tmpa[0][m+3], acc);
            }
        }
        z1f[t] = __fadd_rn(acc, b1g[128+t]);
    }
    __syncthreads();
    if (t < 256) { s1f[t] = sinf(z1f[t]); c1f[t] = cosf(z1f[t]); }
    __syncthreads();
    if (t < 128)      tmpa[0][t] = 1.0f;                          // h1
    else if (t < 256) tmpa[0][t] = s1f[t-128];
    else if (t < 384) tmpa[0][t] = c1f[t-128];
    else              tmpa[0][t] = __fmul_rn(z1f[t-128], z1f[t]);
    __syncthreads();
    if (t < 2) {
        float acc = 0.0f;
        for (int n = 0; n < 512; ++n) acc = fmaf(WoS[t*512 + n], tmpa[0][n], acc);
        yvf[t] = __fadd_rn(acc, bog[t]);
    }
    __syncthreads();

    const float y1 = yvf[0], y2 = yvf[1];

    // theta-gate early exit (bit-exact: reference where() zeroes jcob/h1/h2)
    if (!(y2 > 0.5f)) {
        if (t < 16)  out[s*16 + t] = 0.0f;
        if (t == 16) out[(size_t)B*16 + s] = 0.0f;
        if (t == 17) out[(size_t)B*17 + s] = y2;
        return;
    }

    const float y2sq = __fmul_rn(y2, y2);
    const float r2 = 1.0f / y2sq;                       // integer_pow(y2,-2)
    const float r3 = 1.0f / __fmul_rn(y2sq, y2);        // integer_pow(y2,-3)
    const float sd1f = 1.0f / y2;                       // div VJP wrt numerator
    const float sd2f = __fmul_rn(-y1, r2);              // mul(mul(neg(ct),y1),y2^-2)

    // ---- base reverse pass ----
    if (t < 384) {
        float acc = fmaf(WoS[128+t], sd1f, 0.0f);
        whatf[t] = fmaf(WoS[512+128+t], sd2f, acc);
    }
    __syncthreads();
    {
        float v;
        if (t < 128)      v =  __fmul_rn(whatf[t],     c1f[t]);
        else if (t < 256) v = -__fmul_rn(whatf[t],     s1f[t]);
        else if (t < 384) v =  __fmul_rn(whatf[t],     z1f[t+128]);
        else              v =  __fmul_rn(whatf[t-128], z1f[t-128]);
        tmpa[0][t] = v;
    }
    __syncthreads();
    if (t < 384) {
        const float* wc = &W1g[(size_t)128*512 + 128 + t];
        float acc = 0.0f;
        for (int p = 0; p < 512; ++p) acc = fmaf(tmpa[0][p], wc[(size_t)p*512], acc);
        v0f[t] = acc;
    }
    __syncthreads();
    {
        float v;
        if (t < 128)      v =  __fmul_rn(v0f[t],     c0f[t]);
        else if (t < 256) v = -__fmul_rn(v0f[t],     s0f[t]);
        else if (t < 384) v =  __fmul_rn(v0f[t],     z0f[t+128]);
        else              v =  __fmul_rn(v0f[t-128], z0f[t-128]);
        tmpa[0][t] = v;
    }
    __syncthreads();
    if (t < 32) {
        float acc = 0.0f;
        for (int p = 0; p < 512; ++p) acc = fmaf(tmpa[0][p], W0g[(128+p)*32 + t], acc);
        Hf[t][16] = acc;
    }
    __syncthreads();

    // ---- 16 tangent passes: 4 groups of 4 ----
    for (int g = 0; g < 4; ++g) {
        const int cj0 = 16 + g*4;

        // hd0 for 4 columns (verbatim R11; pool = hd0a)
        if (t < 384) {
            if (t < 128) {
                const float4 e = *(const float4*)&W0g[(128+t)*32 + cj0];
                const float cth = c0f[t];
                hd0a[0][t] = __fmul_rn(cth, e.x);
                hd0a[1][t] = __fmul_rn(cth, e.y);
                hd0a[2][t] = __fmul_rn(cth, e.z);
                hd0a[3][t] = __fmul_rn(cth, e.w);
            } else if (t < 256) {
                const float4 e = *(const float4*)&W0g[(128+t)*32 + cj0];
                const float sth = s0f[t];
                hd0a[0][t] = -__fmul_rn(sth, e.x);
                hd0a[1][t] = -__fmul_rn(sth, e.y);
                hd0a[2][t] = -__fmul_rn(sth, e.z);
                hd0a[3][t] = -__fmul_rn(sth, e.w);
            } else {
                const int i = t - 256;
                const float4 p4 = *(const float4*)&W0g[(384+i)*32 + cj0];
                const float4 q4 = *(const float4*)&W0g[(512+i)*32 + cj0];
                const float za = z0f[384+i], zb = z0f[256+i];
                hd0a[0][t] = __fadd_rn(__fmul_rn(p4.x, za), __fmul_rn(zb, q4.x));
                hd0a[1][t] = __fadd_rn(__fmul_rn(p4.y, za), __fmul_rn(zb, q4.y));
                hd0a[2][t] = __fadd_rn(__fmul_rn(p4.z, za), __fmul_rn(zb, q4.z));
                hd0a[3][t] = __fadd_rn(__fmul_rn(p4.w, za), __fmul_rn(zb, q4.w));
            }
        }
        __syncthreads();

        // zd1 for 4 columns (verbatim R11: one coalesced w1t sweep, 4 chains)
        {
            float a0=0.0f, a1=0.0f, a2=0.0f, a3=0.0f;
            if (w1t) {
                const float* wt = &w1t[(size_t)128*512 + t];
                for (int m = 0; m < 384; ++m) {
                    const float w = wt[(size_t)m*512];
                    a0 = fmaf(w, hd0a[0][m], a0);
                    a1 = fmaf(w, hd0a[1][m], a1);
                    a2 = fmaf(w, hd0a[2][m], a2);
                    a3 = fmaf(w, hd0a[3][m], a3);
                }
            } else {
                const float* wr = &W1g[(size_t)(128+t)*512 + 128];
                for (int m = 0; m < 384; m += 4) {
                    const float4 w  = *(const float4*)(wr + m);
                    const float4 h0 = *(const float4*)&hd0a[0][m];
                    const float4 h1 = *(const float4*)&hd0a[1][m];
                    const float4 h2 = *(const float4*)&hd0a[2][m];
                    const float4 h3 = *(const float4*)&hd0a[3][m];
                    a0 = fmaf(w.x, h0.x, a0); a0 = fmaf(w.y, h0.y, a0);
                    a0 = fmaf(w.z, h0.z, a0); a0 = fmaf(w.w, h0.w, a0);
                    a1 = fmaf(w.x, h1.x, a1); a1 = fmaf(w.y, h1.y, a1);
                    a1 = fmaf(w.z, h1.z, a1); a1 = fmaf(w.w, h1.w, a1);
                    a2 = fmaf(w.x, h2.x, a2); a2 = fmaf(w.y, h2.y, a2);
                    a2 = fmaf(w.z, h2.z, a2); a2 = fmaf(w.w, h2.w, a2);
                    a3 = fmaf(w.x, h3.x, a3); a3 = fmaf(w.y, h3.y, a3);
                    a3 = fmaf(w.z, h3.z, a3); a3 = fmaf(w.w, h3.w, a3);
                }
            }
            zd1a[0][t]=a0; zd1a[1][t]=a1; zd1a[2][t]=a2; zd1a[3][t]=a3;
        }
        __syncthreads();                 // hd0a dead from here; pool -> h1df

        // first sub-loop: h1d, ydf, vdot1 -- VERBATIM R11, vdot1 -> tmpa[jj]
        for (int jj = 0; jj < 4; ++jj) {
            const float* zd1f = zd1a[jj];
            {
                float v;
                if (t < 128)      v = 0.0f;
                else if (t < 256) v =  __fmul_rn(c1f[t-128], zd1f[t-128]);
                else if (t < 384) v = -__fmul_rn(s1f[t-128], zd1f[t-128]);
                else              v = __fadd_rn(__fmul_rn(zd1f[t-128], z1f[t]),
                                                __fmul_rn(z1f[t-128], zd1f[t]));
                h1df[t] = v;
            }
            __syncthreads();
            if (t < 2) {
                float acc = 0.0f;
                for (int n = 0; n < 512; ++n) acc = fmaf(WoS[t*512 + n], h1df[n], acc);
                ydf[t] = acc;
            }
            __syncthreads();
            {   // vdot1, jax-JVP associations (verbatim R11)
                float yd1 = ydf[0], yd2 = ydf[1];
                float sdot1 = __fmul_rn(-yd2, r2);
                float dr2 = __fmul_rn(__fmul_rn(yd2, -2.0f), r3);
                float sdot2 = __fadd_rn(__fmul_rn(-yd1, r2), __fmul_rn(-y1, dr2));
                int n = (t < 384) ? (128 + t) : t;
                float wd = fmaf(WoS[512+n], sdot2, fmaf(WoS[n], sdot1, 0.0f));
                float v;
                if (t < 128) {
                    float dcs = __fmul_rn(zd1f[t], -s1f[t]);
                    v = __fadd_rn(__fmul_rn(wd, c1f[t]), __fmul_rn(whatf[t], dcs));
                } else if (t < 256) {
                    float dsn = __fmul_rn(zd1f[t], c1f[t]);
                    v = __fadd_rn(__fmul_rn(wd, -s1f[t]), __fmul_rn(whatf[t], -dsn));
                } else if (t < 384) {
                    v = __fadd_rn(__fmul_rn(wd, z1f[t+128]),
                                  __fmul_rn(whatf[t], zd1f[t+128]));
                } else {
                    v = __fadd_rn(__fmul_rn(wd, z1f[t-128]),
                                  __fmul_rn(whatf[t-128], zd1f[t-128]));
                }
                tmpa[jj][t] = v;
            }
            __syncthreads();             // h1df dead after jj=3; pool -> vd0a
        }

        // vd0: ONE coalesced W1-column sweep feeds 4 ascending chains (R11)
        if (t < 384) {
            const float* wc = &W1g[(size_t)128*512 + 128 + t];
            float a0=0.0f, a1=0.0f, a2=0.0f, a3=0.0f;
            for (int p = 0; p < 512; ++p) {
                const float w = wc[(size_t)p*512];
                a0 = fmaf(tmpa[0][p], w, a0);
                a1 = fmaf(tmpa[1][p], w, a1);
                a2 = fmaf(tmpa[2][p], w, a2);
                a3 = fmaf(tmpa[3][p], w, a3);
            }
            vd0a[0][t]=a0; vd0a[1][t]=a1; vd0a[2][t]=a2; vd0a[3][t]=a3;
        }
        __syncthreads();

        // second sub-loop: dzdot0 + Hf -- VERBATIM R11 per jj
        for (int jj = 0; jj < 4; ++jj) {
            const int j = g*4 + jj;
            const int cj = 16 + j;
            const float* vd0f = vd0a[jj];
            {
                float v;
                if (t < 128) {
                    float e = W0g[(128+t)*32 + cj];
                    float dcs = __fmul_rn(e, -s0f[t]);
                    v = __fadd_rn(__fmul_rn(vd0f[t], c0f[t]), __fmul_rn(v0f[t], dcs));
                } else if (t < 256) {
                    float e = W0g[(128+t)*32 + cj];
                    float dsn = __fmul_rn(e, c0f[t]);
                    v = __fadd_rn(__fmul_rn(vd0f[t], -s0f[t]), __fmul_rn(v0f[t], -dsn));
                } else if (t < 384) {
                    float eb = W0g[(256+t)*32 + cj];
                    v = __fadd_rn(__fmul_rn(vd0f[t], z0f[t+128]), __fmul_rn(v0f[t], eb));
                } else {
                    float ea = W0g[t*32 + cj];
                    v = __fadd_rn(__fmul_rn(vd0f[t-128], z0f[t-128]), __fmul_rn(v0f[t-128], ea));
                }
                tmpa[jj][t] = v;
            }
            __syncthreads();
            if (t < 32) {
                float acc = 0.0f;
                for (int p = 0; p < 512; ++p)
                    acc = fmaf(tmpa[jj][p], W0g[(128+p)*32 + t], acc);
                Hf[t][j] = acc;
            }
            __syncthreads();             // vd0a dead after jj=3 of g=3
        }
    }

    // ---- A = h1 + eps I; rhs = jcob - h2@q  (pool -> solve arrays) ----
    if (t < 256) {
        int i = t >> 4, jj = t & 15;
        Af[i][jj] = (i == jj) ? __fadd_rn(Hf[16+i][jj], 1.0e-3f) : Hf[16+i][jj];
    }
    if (t >= 256 && t < 272) {
        int i = t - 256;
        float dd = 0.0f;
        for (int jj = 0; jj < 16; ++jj) dd = fmaf(Hf[i][jj], uf[jj], dd);
        rf[i] = __fsub_rn(Hf[i][16], dd);
    }
    __syncthreads();

    // sgetf2
    for (int j = 0; j < 16; ++j) {
        if (t == 0) {
            int p = j; float best = fabsf(Af[j][j]);
            for (int r = j+1; r < 16; ++r) {
                float v = fabsf(Af[r][j]);
                if (v > best) { best = v; p = r; }
            }
            ipiv[j] = p; pivS = p;
        }
        __syncthreads();
        int piv = pivS;
        if (piv != j && t < 16) {
            float tv = Af[j][t]; Af[j][t] = Af[piv][t]; Af[piv][t] = tv;
        }
        __syncthreads();
        float recip = 1.0f / Af[j][j];
        if (t > j && t < 16) Af[t][j] = __fmul_rn(Af[t][j], recip);
        __syncthreads();
        if (t < 256) {
            int i = t >> 4, k = t & 15;
            if (i > j && k > j) Af[i][k] = fmaf(-Af[i][j], Af[j][k], Af[i][k]);
        }
        __syncthreads();
    }

    // sgetri: strti2 + descending-j sweep + reverse column pivots
    if (t == 0) {
        for (int j = 0; j < 16; ++j) {
            float ajj_inv = 1.0f / Af[j][j];
            Af[j][j] = ajj_inv;
            float ajj = -ajj_inv;
            for (int j2 = 0; j2 < j; ++j2) {
                float temp = Af[j2][j];
                if (temp != 0.0f)
                    for (int i = 0; i < j2; ++i)
                        Af[i][j] = fmaf(temp, Af[i][j2], Af[i][j]);
                Af[j2][j] = __fmul_rn(Af[j2][j], Af[j2][j2]);
            }
            for (int i = 0; i < j; ++i) Af[i][j] = __fmul_rn(Af[i][j], ajj);
        }
    }
    __syncthreads();
    for (int j = 15; j >= 0; --j) {
        if (t > j && t < 16) { wkc[t] = Af[t][j]; Af[t][j] = 0.0f; }
        __syncthreads();
        if (t < 16) {
            float acc = Af[t][j];
            for (int k = j+1; k < 16; ++k) acc = fmaf(-wkc[k], Af[t][k], acc);
            Af[t][j] = acc;
        }
        __syncthreads();
    }
    if (t < 16) {
        for (int j = 15; j >= 0; --j) {
            int jp = ipiv[j];
            if (jp != j) { float tv = Af[t][j]; Af[t][j] = Af[t][jp]; Af[t][jp] = tv; }
        }
    }
    __syncthreads();

    // qdd = inv @ rhs
    if (t < 16) {
        float acc = 0.0f;
        for (int jj = 0; jj < 16; ++jj) acc = fmaf(Af[t][jj], rf[jj], acc);
        qdo[t] = acc;
    }
    __syncthreads();

    // ---- outputs (gate is true on this path) ----
    if (t < 16)  out[s*16 + t] = qdo[t];
    if (t == 16) out[(size_t)B*16 + s] = y1 / y2;
    if (t == 17) out[(size_t)B*17 + s] = y2;
}

extern "C" void kernel_launch(void* const* d_in, const int* in_sizes, int n_in,
                              void* d_out, int out_size, void* d_ws, size_t ws_size,
                              hipStream_t stream) {
    (void)n_in; (void)out_size;
    const float* x  = (const float*)d_in[0];
    const float* W0 = (const float*)d_in[1];
    const float* b0 = (const float*)d_in[2];
    const float* W1 = (const float*)d_in[3];
    const float* b1 = (const float*)d_in[4];
    const float* Wo = (const float*)d_in[5];
    const float* bo = (const float*)d_in[6];
    const int B = in_sizes[0] / 32;
    const size_t need = (size_t)512 * 512 * sizeof(float);
    float* w1t = (d_ws != nullptr && ws_size >= need) ? (float*)d_ws : nullptr;
    if (w1t) {
        hipLaunchKernelGGL(transpose_w1, dim3((512*512 + 255)/256), dim3(256), 0, stream,
                           W1, w1t);
    }
    hipLaunchKernelGGL(leql_f32_kernel, dim3(B), dim3(512), 0, stream,
                       x, W0, b0, W1, b1, Wo, bo, w1t, (float*)d_out, B);
}